// Round 3
// baseline (8091.305 us; speedup 1.0000x reference)
//
#include <hip/hip_runtime.h>
#include <hip/hip_bf16.h>
#include <hip/hip_cooperative_groups.h>
#include <math.h>

namespace cg = cooperative_groups;

#define B   128
#define NN  36
#define FF  2048
#define AA  1024
#define EE  1024
#define DD  1024
#define VV  10000
#define LL  20
#define TT  19

typedef __attribute__((ext_vector_type(8))) short short8;
typedef __attribute__((ext_vector_type(4))) float floatx4;

// ---------------- sort (stable descending by length) ----------------
__global__ __launch_bounds__(B) void sort_kernel(const int* __restrict__ cap_len,
                                                 int* __restrict__ sort_ind,
                                                 int* __restrict__ dec_len) {
    __shared__ int lsh[B];
    int i = threadIdx.x;
    lsh[i] = cap_len[i];
    __syncthreads();
    int li = lsh[i];
    int rank = 0;
    for (int j = 0; j < B; ++j) {
        int lj = lsh[j];
        rank += (lj > li) || (lj == li && j < i);   // stable descending
    }
    sort_ind[rank] = i;
    dec_len[rank]  = li - 1;
}

// ---------------- fp32 -> bf16 convert ----------------
__global__ void convert_kernel(const float* __restrict__ src,
                               __hip_bfloat16* __restrict__ dst, int n) {
    int i = blockIdx.x * 256 + threadIdx.x;
    if (i < n) dst[i] = __float2bfloat16(src[i]);
}

// ---------------- pack [W1_ih | W1_hh] -> bf16 (4096 x 5120) ----------------
__global__ void pack_w1_kernel(const float* __restrict__ Wih,
                               const float* __restrict__ Whh,
                               __hip_bfloat16* __restrict__ dst) {
    int i = blockIdx.x * 256 + threadIdx.x;
    int n = i / 5120, k = i % 5120;
    float v = (k < 4096) ? Wih[(size_t)n * 4096 + k] : Whh[(size_t)n * 1024 + (k - 4096)];
    dst[i] = __float2bfloat16(v);
}

// ---------------- pack [W2_ih | W2_hh] -> bf16 (4096 x 4096) ----------------
__global__ void pack_w2_kernel(const float* __restrict__ Wih,
                               const float* __restrict__ Whh,
                               __hip_bfloat16* __restrict__ dst) {
    int i = blockIdx.x * 256 + threadIdx.x;
    int n = i >> 12, k = i & 4095;
    float v = (k < 3072) ? Wih[(size_t)n * 3072 + k] : Whh[(size_t)n * 1024 + (k - 3072)];
    dst[i] = __float2bfloat16(v);
}

// ---------------- sorted feats -> bf16 ----------------
__global__ void feats_bf_kernel(const float* __restrict__ img,
                                const int* __restrict__ sort_ind,
                                __hip_bfloat16* __restrict__ dst) {
    int i = blockIdx.x * 256 + threadIdx.x;
    int b = i / (NN * FF);
    int r = i % (NN * FF);
    dst[i] = __float2bfloat16(img[(size_t)sort_ind[b] * (NN * FF) + r]);
}

// ---------------- feats_mean -> x1full slot [1024..3072) ----------------
__global__ void fm_kernel(const float* __restrict__ img,
                          const int* __restrict__ sort_ind,
                          __hip_bfloat16* __restrict__ x1full) {
    int i = blockIdx.x * 256 + threadIdx.x;
    int b = i >> 11;
    int f = i & 2047;
    const float* src = img + (size_t)sort_ind[b] * (NN * FF) + f;
    float s = 0.f;
#pragma unroll
    for (int n = 0; n < NN; ++n) s += src[n * FF];
    x1full[(size_t)b * 5120 + 1024 + f] = __float2bfloat16(s * (1.0f / NN));
}

// ---------------- emb gather (t=0 only) ----------------
__global__ void emb_gather_kernel(const float* __restrict__ emb,
                                  const int* __restrict__ caps,
                                  const int* __restrict__ sort_ind,
                                  int t,
                                  __hip_bfloat16* __restrict__ x1full) {
    int i = blockIdx.x * 256 + threadIdx.x;
    int b = i >> 10;
    int e = i & 1023;
    int cap = caps[sort_ind[b] * LL + t];
    x1full[(size_t)b * 5120 + 3072 + e] = __float2bfloat16(emb[(size_t)cap * EE + e]);
}

// ---------------- bf16 MFMA GEMM core ----------------
// EPI=0: fp32 partial at C. EPI=1: preds epilogue (bias+mask+N guard).
// EPI=2: bf16 output (att1).
#define BM 128
#define BN 64
#define BK 64
#define LDS_K 72

template<int EPI>
__device__ __forceinline__ void gemm_core(
        short (*As)[LDS_K], short (*Wsm)[LDS_K],
        int bm, int bn, int k0,
        const __hip_bfloat16* __restrict__ A, int lda,
        const __hip_bfloat16* __restrict__ W, int ldw,
        float* __restrict__ C, int ldc,
        int N, int Kc,
        const float* __restrict__ bias,
        const int* __restrict__ dec_len, int tstep) {
    const int tid  = threadIdx.x;
    const int lane = tid & 63;
    const int wv   = tid >> 6;
    const int quad = lane >> 4;
    const int l15  = lane & 15;
    const int wm   = (wv >> 1) * 64;
    const int wn   = (wv & 1) * 32;
    const int srow = tid >> 3;
    const int scol = (tid & 7) * 8;

    floatx4 acc[4][2];
#pragma unroll
    for (int i = 0; i < 4; ++i)
#pragma unroll
        for (int j = 0; j < 2; ++j)
            acc[i][j] = (floatx4){0.f, 0.f, 0.f, 0.f};

    const __hip_bfloat16* Aptr = A + (size_t)(bm + srow) * lda + k0 + scol;
    const __hip_bfloat16* Wptr = W + k0 + scol;

    for (int kt = 0; kt < Kc; kt += BK) {
#pragma unroll
        for (int p = 0; p < 4; ++p) {
            floatx4 v = *(const floatx4*)(Aptr + (size_t)(p * 32) * lda + kt);
            *(floatx4*)(&As[p * 32 + srow][scol]) = v;
        }
#pragma unroll
        for (int p = 0; p < 2; ++p) {
            int gw = bn + p * 32 + srow;
            floatx4 v;
            if (EPI != 1 || gw < N)
                v = *(const floatx4*)(Wptr + (size_t)gw * ldw + kt);
            else
                v = (floatx4){0.f, 0.f, 0.f, 0.f};
            *(floatx4*)(&Wsm[p * 32 + srow][scol]) = v;
        }
        __syncthreads();
#pragma unroll
        for (int ks = 0; ks < 2; ++ks) {
            short8 af[4], bw[2];
#pragma unroll
            for (int i = 0; i < 4; ++i)
                af[i] = *(const short8*)(&As[wm + i * 16 + l15][ks * 32 + quad * 8]);
#pragma unroll
            for (int j = 0; j < 2; ++j)
                bw[j] = *(const short8*)(&Wsm[wn + j * 16 + l15][ks * 32 + quad * 8]);
#pragma unroll
            for (int i = 0; i < 4; ++i)
#pragma unroll
                for (int j = 0; j < 2; ++j)
                    acc[i][j] = __builtin_amdgcn_mfma_f32_16x16x32_bf16(
                        af[i], bw[j], acc[i][j], 0, 0, 0);
        }
        __syncthreads();
    }

    // D layout: row = quad*4+reg, col = lane&15 (m89-verified)
#pragma unroll
    for (int i = 0; i < 4; ++i) {
        int m = bm + wm + i * 16 + quad * 4;
#pragma unroll
        for (int j = 0; j < 2; ++j) {
            int n = bn + wn + j * 16 + l15;
            if (EPI == 1 && n >= N) continue;
#pragma unroll
            for (int r = 0; r < 4; ++r) {
                float v = acc[i][j][r];
                if (EPI == 1) {
                    bool act = tstep < dec_len[m + r];
                    v = act ? (v + bias[n]) : 0.f;
                    C[(size_t)(m + r) * ldc + n] = v;
                } else if (EPI == 2) {
                    ((__hip_bfloat16*)C)[(size_t)(m + r) * ldc + n] = __float2bfloat16(v);
                } else {
                    C[(size_t)(m + r) * ldc + n] = v;
                }
            }
        }
    }
}

// ---------------- LSTM pointwise element (NZ split-K partials) ----------------
template<int NZ>
__device__ __forceinline__ void lstm_elem(
        int idx, const float* __restrict__ gpart, size_t pstride,
        const float* __restrict__ bih, const float* __restrict__ bhh,
        float* __restrict__ c,
        __hip_bfloat16* __restrict__ hs1, int st1,
        __hip_bfloat16* __restrict__ hs2, int st2,
        const int* __restrict__ dec_len, int t,
        const float* __restrict__ embF,
        const int* __restrict__ caps,
        const int* __restrict__ sort_ind,
        __hip_bfloat16* __restrict__ embdst, int tnext) {
    int b = idx >> 10;
    int d = idx & 1023;
    bool act = t < dec_len[b];
    if (embdst && act) {
        int cap = caps[sort_ind[b] * LL + tnext];
        embdst[(size_t)b * 5120 + d] = __float2bfloat16(embF[(size_t)cap * EE + d]);
    }
    if (!act) return;
    float g[4];
#pragma unroll
    for (int gate = 0; gate < 4; ++gate) {
        size_t o = (size_t)b * 4096 + gate * 1024 + d;
        float s = bih[gate * 1024 + d] + bhh[gate * 1024 + d];
#pragma unroll
        for (int z = 0; z < NZ; ++z) s += gpart[z * pstride + o];
        g[gate] = s;
    }
    float si = 1.f / (1.f + expf(-g[0]));
    float sf = 1.f / (1.f + expf(-g[1]));
    float so = 1.f / (1.f + expf(-g[3]));
    float cc = sf * c[idx] + si * tanhf(g[2]);
    float hh = so * tanhf(cc);
    c[idx] = cc;
    __hip_bfloat16 hb = __float2bfloat16(hh);
    hs1[(size_t)b * st1 + d] = hb;
    hs2[(size_t)b * st2 + d] = hb;
}

// ================= persistent cooperative mega-kernel: whole time loop =================
// Replaces 6 kernel boundaries/step with 8 grid syncs/step.
// g_part layout: z0..7 = g1 (Kc=640) then reused for g2-awe (Kc=256, K 0..2048);
//                z8..11 = g2-h (Kc=512, K 2048..4096). lstm1 sums 8, lstm2 sums 12.
__global__ __launch_bounds__(256, 2) void mega_kernel(
        __hip_bfloat16* x1full, __hip_bfloat16* x2full,
        const __hip_bfloat16* W1cat, const __hip_bfloat16* W2cat,
        const __hip_bfloat16* Wd_bf, const __hip_bfloat16* Wfc_bf,
        float* g_part, float* att2_part, float* av_g, float* escore,
        const __hip_bfloat16* feats_bf, const __hip_bfloat16* att1_bf,
        const float* Wa, const float* bf_, const float* bd_,
        const float* b1_ih, const float* b1_hh,
        const float* b2_ih, const float* b2_hh, const float* bfc,
        float* c1, float* c2,
        const int* dec_len, const int* caps, const int* sort_ind,
        const float* embF, float* out) {
    cg::grid_group grid = cg::this_grid();
    __shared__ __align__(16) short As[BM][LDS_K];
    __shared__ __align__(16) short Wsm[BN][LDS_K];
    __shared__ float alpha[64];

    const size_t gstride = (size_t)B * 4096;
    const size_t astride = (size_t)B * AA;
    const int tid = threadIdx.x;
    const int nthr = gridDim.x * 256;

    for (int t = 0; t < TT; ++t) {
        // ---- P1: g1 = x1full @ W1cat^T, split-K 8 (512 tasks) ----
        for (int task = blockIdx.x; task < 512; task += gridDim.x) {
            int bx = task & 63, bz = task >> 6;
            gemm_core<0>(As, Wsm, 0, bx * BN, bz * 640,
                         x1full, 5120, W1cat, 5120,
                         g_part + (size_t)bz * gstride, 4096,
                         4096, 640, nullptr, nullptr, 0);
        }
        grid.sync();

        // ---- P2: lstm1 pointwise (B*DD elems) ----
        for (int idx = blockIdx.x * 256 + tid; idx < B * DD; idx += nthr)
            lstm_elem<8>(idx, g_part, gstride, b1_ih, b1_hh, c1,
                         x1full + 4096, 5120, x2full + 2048, 4096, dec_len, t,
                         nullptr, nullptr, nullptr, nullptr, 0);
        grid.sync();

        // ---- P3: g2-h half (256) + preds(t-1) (157, t>0) + att2 (256) ----
        {
            int n3 = (t > 0) ? 669 : 512;
            for (int task = blockIdx.x; task < n3; task += gridDim.x) {
                if (task < 256) {                 // g2 h-part: K 2048..4096
                    int bx = task & 63, z = task >> 6;
                    gemm_core<0>(As, Wsm, 0, bx * BN, 2048 + z * 512,
                                 x2full, 4096, W2cat, 4096,
                                 g_part + (size_t)(8 + z) * gstride, 4096,
                                 4096, 512, nullptr, nullptr, 0);
                } else if (t > 0 && task < 413) { // preds for t-1 (off critical path)
                    int px = task - 256;
                    gemm_core<1>(As, Wsm, 0, px * BN, 0,
                                 x1full, 5120, Wfc_bf, DD,
                                 out + (size_t)(t - 1) * VV, TT * VV,
                                 VV, DD, bfc, dec_len, t - 1);
                } else {                          // att2 partials: h1 @ Wd^T
                    int a2 = task - ((t > 0) ? 413 : 256);
                    int bx = a2 & 15, z = a2 >> 4;
                    gemm_core<0>(As, Wsm, 0, bx * BN, z * 64,
                                 x2full + 2048, 4096, Wd_bf, DD,
                                 att2_part + (size_t)z * astride, AA,
                                 AA, 64, nullptr, nullptr, 0);
                }
            }
        }
        grid.sync();

        // ---- P4: av = bf + bd + sum_z att2 partials (512 tasks of 256 elems) ----
        for (int task = blockIdx.x; task < 512; task += gridDim.x) {
            int b = task >> 2;
            int a = (task & 3) * 256 + tid;
            size_t o = (size_t)b * AA + a;
            float s = bf_[a] + bd_[a];
#pragma unroll
            for (int z = 0; z < 16; ++z) s += att2_part[z * astride + o];
            av_g[o] = s;
        }
        grid.sync();

        // ---- P5: scores e[b,n] (1152 tasks, wave per (b,n)) ----
        for (int task = blockIdx.x; task < (B * NN) / 4; task += gridDim.x) {
            int wv = tid >> 6, lane = tid & 63;
            int idx = task * 4 + wv;
            int b = idx / NN;
            const __hip_bfloat16* a1 = att1_bf + (size_t)idx * AA + lane * 16;
            const float* avp = av_g + (size_t)b * AA + lane * 16;
            const float* wap = Wa + lane * 16;
            float pacc = 0.f;
#pragma unroll
            for (int h = 0; h < 2; ++h) {
                short8 a8 = *(const short8*)(a1 + h * 8);
                floatx4 v0 = *(const floatx4*)(avp + h * 8);
                floatx4 v1 = *(const floatx4*)(avp + h * 8 + 4);
                floatx4 w0 = *(const floatx4*)(wap + h * 8);
                floatx4 w1 = *(const floatx4*)(wap + h * 8 + 4);
                float af[8];
#pragma unroll
                for (int q = 0; q < 8; ++q) {
                    union { short s; __hip_bfloat16 b; } u; u.s = a8[q];
                    af[q] = __bfloat162float(u.b);
                }
#pragma unroll
                for (int q = 0; q < 4; ++q) {
                    pacc += fmaxf(af[q] + v0[q], 0.f) * w0[q];
                    pacc += fmaxf(af[4 + q] + v1[q], 0.f) * w1[q];
                }
            }
            for (int off = 32; off; off >>= 1) pacc += __shfl_down(pacc, off);
            if (lane == 0) escore[idx] = pacc;
        }
        grid.sync();

        // ---- P6: softmax(e) + awe chunk -> x2full awe slot (512 tasks) ----
        for (int task = blockIdx.x; task < 512; task += gridDim.x) {
            int b = task >> 2, chunk = task & 3;
            if (tid < 64) {
                float ev = (tid < NN) ? escore[b * NN + tid] : -INFINITY;
                float m = ev;
                for (int off = 32; off; off >>= 1) m = fmaxf(m, __shfl_down(m, off));
                m = __shfl(m, 0);
                float ex = (tid < NN) ? expf(ev - m) : 0.f;
                float s = ex;
                for (int off = 32; off; off >>= 1) s += __shfl_down(s, off);
                s = __shfl(s, 0);
                if (tid < NN) alpha[tid] = ex / s;
            }
            __syncthreads();
            int f0 = chunk * 512 + tid * 2;
            const __hip_bfloat16* src = feats_bf + (size_t)b * (NN * FF) + f0;
            float s0 = 0.f, s1 = 0.f;
#pragma unroll
            for (int n = 0; n < NN; ++n) {
                __hip_bfloat162 v = *(const __hip_bfloat162*)(src + n * FF);
                float af = alpha[n];
                s0 += af * __bfloat162float(v.x);
                s1 += af * __bfloat162float(v.y);
            }
            __hip_bfloat162 o;
            o.x = __float2bfloat16(s0);
            o.y = __float2bfloat16(s1);
            *(__hip_bfloat162*)(x2full + (size_t)b * 4096 + f0) = o;
            __syncthreads();
        }
        grid.sync();

        // ---- P7: g2 awe-half: K 0..2048, split-K 8 (512 tasks) ----
        for (int task = blockIdx.x; task < 512; task += gridDim.x) {
            int bx = task & 63, z = task >> 6;
            gemm_core<0>(As, Wsm, 0, bx * BN, z * 256,
                         x2full, 4096, W2cat, 4096,
                         g_part + (size_t)z * gstride, 4096,
                         4096, 256, nullptr, nullptr, 0);
        }
        grid.sync();

        // ---- P8: lstm2 pointwise (sums 12 partials) + emb gather for t+1 ----
        for (int idx = blockIdx.x * 256 + tid; idx < B * DD; idx += nthr)
            lstm_elem<12>(idx, g_part, gstride, b2_ih, b2_hh, c2,
                          x1full + 0, 5120, x2full + 3072, 4096, dec_len, t,
                          embF, caps, sort_ind,
                          (t + 1 < TT) ? (x1full + 3072) : nullptr, t + 1);
        grid.sync();
    }

    // ---- final preds for t = TT-1 ----
    for (int task = blockIdx.x; task < 157; task += gridDim.x)
        gemm_core<1>(As, Wsm, 0, task * BN, 0,
                     x1full, 5120, Wfc_bf, DD,
                     out + (size_t)(TT - 1) * VV, TT * VV,
                     VV, DD, bfc, dec_len, TT - 1);
}

// ================= fallback-path kernels (proven R1 schedule) =================
template<int EPI>
__global__ __launch_bounds__(256) void gemm_bf16(
        const __hip_bfloat16* __restrict__ A, int lda,
        const __hip_bfloat16* __restrict__ W, int ldw,
        float* __restrict__ C, int ldc, size_t pstride,
        int N, int Kc,
        const float* __restrict__ bias,
        const int* __restrict__ dec_len, int tstep) {
    __shared__ __align__(16) short As[BM][LDS_K];
    __shared__ __align__(16) short Wsm[BN][LDS_K];
    gemm_core<EPI>(As, Wsm, blockIdx.y * BM, blockIdx.x * BN, blockIdx.z * Kc,
                   A, lda, W, ldw, C + (size_t)blockIdx.z * pstride, ldc,
                   N, Kc, bias, dec_len, tstep);
}

__global__ __launch_bounds__(256) void gemm_g1_preds(
        const __hip_bfloat16* __restrict__ x1full,
        const __hip_bfloat16* __restrict__ W1cat,
        float* __restrict__ g_part, size_t gstride,
        const __hip_bfloat16* __restrict__ Wfc,
        float* __restrict__ pred_out,
        const float* __restrict__ bfc,
        const int* __restrict__ dec_len, int tprev) {
    __shared__ __align__(16) short As[BM][LDS_K];
    __shared__ __align__(16) short Wsm[BN][LDS_K];
    int idx = blockIdx.x;
    if (idx < 512) {
        int bx = idx & 63, bz = idx >> 6;
        gemm_core<0>(As, Wsm, 0, bx * BN, bz * 640,
                     x1full, 5120, W1cat, 5120,
                     g_part + (size_t)bz * gstride, 4096,
                     4096, 640, nullptr, nullptr, 0);
    } else {
        if (!pred_out) return;
        gemm_core<1>(As, Wsm, 0, (idx - 512) * BN, 0,
                     x1full, 5120, Wfc, DD,
                     pred_out, TT * VV,
                     VV, DD, bfc, dec_len, tprev);
    }
}

__global__ void lstm_kernel(const float* __restrict__ gpart, size_t pstride,
                            const float* __restrict__ bih, const float* __restrict__ bhh,
                            float* __restrict__ c,
                            __hip_bfloat16* __restrict__ hs1, int st1,
                            __hip_bfloat16* __restrict__ hs2, int st2,
                            const int* __restrict__ dec_len, int t,
                            const float* __restrict__ embF,
                            const int* __restrict__ caps,
                            const int* __restrict__ sort_ind,
                            __hip_bfloat16* __restrict__ embdst, int tnext) {
    int idx = blockIdx.x * 256 + threadIdx.x;
    lstm_elem<8>(idx, gpart, pstride, bih, bhh, c, hs1, st1, hs2, st2,
                 dec_len, t, embF, caps, sort_ind, embdst, tnext);
}

__global__ __launch_bounds__(256) void att_fused(
        const float* __restrict__ p, size_t pstride,
        const float* __restrict__ bf_,
        const float* __restrict__ bd_,
        float* __restrict__ av_g,
        const __hip_bfloat16* __restrict__ att1,
        const float* __restrict__ Wa,
        const __hip_bfloat16* __restrict__ feats,
        __hip_bfloat16* __restrict__ x2full) {
    int b = blockIdx.x;
    int tid = threadIdx.x;
    __shared__ float esh[NN];
    __shared__ float alpha[NN];

#pragma unroll
    for (int rep = 0; rep < 4; ++rep) {
        int a = rep * 256 + tid;
        size_t o = (size_t)b * AA + a;
        float s = bf_[a] + bd_[a];
#pragma unroll
        for (int z = 0; z < 16; ++z) s += p[z * pstride + o];
        av_g[o] = s;
    }
    __syncthreads();

    int wv = tid >> 6, lane = tid & 63;
    const float* avp = av_g + (size_t)b * AA + lane * 16;
    const float* wap = Wa + lane * 16;
    for (int n = wv; n < NN; n += 4) {
        const __hip_bfloat16* a1 = att1 + ((size_t)b * NN + n) * AA + lane * 16;
        float pacc = 0.f;
#pragma unroll
        for (int h = 0; h < 2; ++h) {
            short8 a8 = *(const short8*)(a1 + h * 8);
            floatx4 v0 = *(const floatx4*)(avp + h * 8);
            floatx4 v1 = *(const floatx4*)(avp + h * 8 + 4);
            floatx4 w0 = *(const floatx4*)(wap + h * 8);
            floatx4 w1 = *(const floatx4*)(wap + h * 8 + 4);
            float af[8];
#pragma unroll
            for (int q = 0; q < 8; ++q) {
                union { short s; __hip_bfloat16 b; } u; u.s = a8[q];
                af[q] = __bfloat162float(u.b);
            }
#pragma unroll
            for (int q = 0; q < 4; ++q) {
                pacc += fmaxf(af[q] + v0[q], 0.f) * w0[q];
                pacc += fmaxf(af[4 + q] + v1[q], 0.f) * w1[q];
            }
        }
        for (int off = 32; off; off >>= 1) pacc += __shfl_down(pacc, off);
        if (lane == 0) esh[n] = pacc;
    }
    __syncthreads();

    if (tid < 64) {
        float ev = (tid < NN) ? esh[tid] : -INFINITY;
        float m = ev;
        for (int off = 32; off; off >>= 1) m = fmaxf(m, __shfl_down(m, off));
        m = __shfl(m, 0);
        float ex = (tid < NN) ? expf(ev - m) : 0.f;
        float s = ex;
        for (int off = 32; off; off >>= 1) s += __shfl_down(s, off);
        s = __shfl(s, 0);
        if (tid < NN) alpha[tid] = ex / s;
    }
    __syncthreads();

    const __hip_bfloat16* src = feats + (size_t)b * (NN * FF) + tid * 8;
    float s[8] = {0.f, 0.f, 0.f, 0.f, 0.f, 0.f, 0.f, 0.f};
#pragma unroll
    for (int n = 0; n < NN; ++n) {
        short8 v = *(const short8*)(src + (size_t)n * FF);
        float al = alpha[n];
#pragma unroll
        for (int q = 0; q < 8; ++q) {
            union { short s_; __hip_bfloat16 b_; } u; u.s_ = v[q];
            s[q] += al * __bfloat162float(u.b_);
        }
    }
    short8 o8;
#pragma unroll
    for (int q = 0; q < 8; ++q) {
        union { short s_; __hip_bfloat16 b_; } u; u.b_ = __float2bfloat16(s[q]);
        o8[q] = u.s_;
    }
    *(short8*)(x2full + (size_t)b * 4096 + tid * 8) = o8;
}

// ---------------- host launcher ----------------
extern "C" void kernel_launch(void* const* d_in, const int* in_sizes, int n_in,
                              void* d_out, int out_size, void* d_ws, size_t ws_size,
                              hipStream_t stream) {
    const float* img     = (const float*)d_in[0];
    const int*   caps    = (const int*)d_in[1];
    const int*   cap_len = (const int*)d_in[2];
    const float* emb     = (const float*)d_in[3];
    const float* W1_ih   = (const float*)d_in[4];
    const float* W1_hh   = (const float*)d_in[5];
    const float* b1_ih   = (const float*)d_in[6];
    const float* b1_hh   = (const float*)d_in[7];
    const float* W2_ih   = (const float*)d_in[8];
    const float* W2_hh   = (const float*)d_in[9];
    const float* b2_ih   = (const float*)d_in[10];
    const float* b2_hh   = (const float*)d_in[11];
    const float* Wf      = (const float*)d_in[12];
    const float* bf      = (const float*)d_in[13];
    const float* Wd      = (const float*)d_in[14];
    const float* bd      = (const float*)d_in[15];
    const float* Wa      = (const float*)d_in[16];
    // d_in[17] = ba: softmax shift-invariant, unused
    const float* Wfc     = (const float*)d_in[18];
    const float* bfc     = (const float*)d_in[19];
    float* out = (float*)d_out;
    (void)in_sizes; (void)n_in; (void)out_size; (void)ws_size;

    char* ws = (char*)d_ws;
    size_t off = 0;
    auto alloc = [&](size_t bytes) -> void* {
        void* p = ws + off;
        off += (bytes + 255) & ~(size_t)255;
        return p;
    };
    int* sort_ind = (int*)alloc(B * sizeof(int));
    int* dec_len  = (int*)alloc(B * sizeof(int));
    __hip_bfloat16* W1cat    = (__hip_bfloat16*)alloc((size_t)4096 * 5120 * 2);
    __hip_bfloat16* W2cat    = (__hip_bfloat16*)alloc((size_t)4096 * 4096 * 2);
    __hip_bfloat16* Wd_bf    = (__hip_bfloat16*)alloc((size_t)AA * DD * 2);
    __hip_bfloat16* Wfc_bf   = (__hip_bfloat16*)alloc((size_t)VV * DD * 2);
    __hip_bfloat16* Wf_bf    = (__hip_bfloat16*)alloc((size_t)AA * FF * 2);
    __hip_bfloat16* feats_bf = (__hip_bfloat16*)alloc((size_t)B * NN * FF * 2);
    __hip_bfloat16* att1_bf  = (__hip_bfloat16*)alloc((size_t)B * NN * AA * 2);
    float* g_part    = (float*)alloc((size_t)12 * B * 4096 * 4);   // 12 slices (mega g2)
    float* att2_part = (float*)alloc((size_t)16 * B * AA * 4);
    float* av        = (float*)alloc((size_t)B * AA * 4);
    float* escore    = (float*)alloc((size_t)B * NN * 4);
    __hip_bfloat16* x1full = (__hip_bfloat16*)alloc((size_t)B * 5120 * 2); // [h2|fm|emb|h1]
    __hip_bfloat16* x2full = (__hip_bfloat16*)alloc((size_t)B * 4096 * 2); // [awe|h1|h2]
    float* c1 = (float*)alloc((size_t)B * DD * 4);
    float* c2 = (float*)alloc((size_t)B * DD * 4);

    // ---- setup ----
    sort_kernel<<<1, B, 0, stream>>>(cap_len, sort_ind, dec_len);
    pack_w1_kernel<<<(4096 * 5120) / 256, 256, 0, stream>>>(W1_ih, W1_hh, W1cat);
    pack_w2_kernel<<<(4096 * 4096) / 256, 256, 0, stream>>>(W2_ih, W2_hh, W2cat);
    convert_kernel<<<(AA * DD) / 256, 256, 0, stream>>>(Wd, Wd_bf, AA * DD);
    convert_kernel<<<(VV * DD + 255) / 256, 256, 0, stream>>>(Wfc, Wfc_bf, VV * DD);
    convert_kernel<<<(AA * FF) / 256, 256, 0, stream>>>(Wf, Wf_bf, AA * FF);
    feats_bf_kernel<<<(B * NN * FF) / 256, 256, 0, stream>>>(img, sort_ind, feats_bf);
    hipMemsetAsync(x1full, 0, (size_t)B * 5120 * 2, stream);
    hipMemsetAsync(x2full, 0, (size_t)B * 4096 * 2, stream);
    hipMemsetAsync(c1, 0, (size_t)B * DD * 4, stream);
    hipMemsetAsync(c2, 0, (size_t)B * DD * 4, stream);
    fm_kernel<<<(B * FF) / 256, 256, 0, stream>>>(img, sort_ind, x1full);
    emb_gather_kernel<<<(B * EE) / 256, 256, 0, stream>>>(emb, caps, sort_ind, 0, x1full);

    // att1 = feats_bf @ Wf^T (bf16 out; bf bias folded into attention av)
    gemm_bf16<2><<<dim3(AA / BN, (B * NN) / BM, 1), 256, 0, stream>>>(
        feats_bf, FF, Wf_bf, FF, (float*)att1_bf, AA, 0, AA, FF, nullptr, nullptr, 0);

    const size_t gstride = (size_t)B * 4096;
    const size_t astride = (size_t)B * AA;

    // ---- persistent cooperative mega-kernel for the whole recurrence ----
    int maxb = 0;
    hipOccupancyMaxActiveBlocksPerMultiprocessor(
        &maxb, reinterpret_cast<const void*>(mega_kernel), 256, 0);
    if (maxb < 1) maxb = 1;
    int mgrid = maxb * 256;            // 256 CUs on MI355X
    if (mgrid > 512) mgrid = 512;

    void* margs[] = {
        (void*)&x1full, (void*)&x2full, (void*)&W1cat, (void*)&W2cat,
        (void*)&Wd_bf, (void*)&Wfc_bf, (void*)&g_part, (void*)&att2_part,
        (void*)&av, (void*)&escore, (void*)&feats_bf, (void*)&att1_bf,
        (void*)&Wa, (void*)&bf, (void*)&bd, (void*)&b1_ih, (void*)&b1_hh,
        (void*)&b2_ih, (void*)&b2_hh, (void*)&bfc, (void*)&c1, (void*)&c2,
        (void*)&dec_len, (void*)&caps, (void*)&sort_ind, (void*)&emb, (void*)&out
    };
    hipError_t merr = hipLaunchCooperativeKernel(
        reinterpret_cast<const void*>(mega_kernel),
        dim3(mgrid), dim3(256), margs, 0, stream);

    if (merr != hipSuccess) {
        // -------- fallback: proven R1 per-step dispatch sequence --------
        for (int t = 0; t < TT; ++t) {
            gemm_g1_preds<<<512 + (VV + BN - 1) / BN, 256, 0, stream>>>(
                x1full, W1cat, g_part, gstride,
                Wfc_bf, (t > 0) ? (out + (size_t)(t - 1) * VV) : nullptr,
                bfc, dec_len, t - 1);
            lstm_kernel<<<(B * DD) / 256, 256, 0, stream>>>(
                g_part, gstride, b1_ih, b1_hh, c1,
                x1full + 4096, 5120, x2full + 2048, 4096, dec_len, t,
                nullptr, nullptr, nullptr, nullptr, 0);
            gemm_bf16<0><<<dim3(AA / BN, 1, 16), 256, 0, stream>>>(
                x2full + 2048, 4096, Wd_bf, DD, att2_part, AA, astride, AA, 64,
                nullptr, nullptr, 0);
            att_fused<<<B, 256, 0, stream>>>(att2_part, astride, bf, bd, av,
                                             att1_bf, Wa, feats_bf, x2full);
            gemm_bf16<0><<<dim3(4096 / BN, 1, 8), 256, 0, stream>>>(
                x2full, 4096, W2cat, 4096, g_part, 4096, gstride, 4096, 512,
                nullptr, nullptr, 0);
            lstm_kernel<<<(B * DD) / 256, 256, 0, stream>>>(
                g_part, gstride, b2_ih, b2_hh, c2,
                x1full + 0, 5120, x2full + 3072, 4096, dec_len, t,
                emb, caps, sort_ind, (t + 1 < TT) ? (x1full + 3072) : nullptr, t + 1);
        }
        gemm_bf16<1><<<dim3((VV + BN - 1) / BN, 1, 1), 256, 0, stream>>>(
            x1full, 5120, Wfc_bf, DD, out + (size_t)(TT - 1) * VV, TT * VV, 0, VV, DD,
            bfc, dec_len, TT - 1);
    }
}

// Round 5
// 1695.813 us; speedup vs baseline: 4.7713x; 4.7713x over previous
//
#include <hip/hip_runtime.h>
#include <hip/hip_bf16.h>
#include <math.h>

#define B   128
#define NN  36
#define FF  2048
#define AA  1024
#define EE  1024
#define DD  1024
#define VV  10000
#define LL  20
#define TT  19

typedef __attribute__((ext_vector_type(8))) short short8;
typedef __attribute__((ext_vector_type(4))) float floatx4;

// ---------------- sort (stable descending by length) ----------------
__global__ __launch_bounds__(B) void sort_kernel(const int* __restrict__ cap_len,
                                                 int* __restrict__ sort_ind,
                                                 int* __restrict__ dec_len) {
    __shared__ int lsh[B];
    int i = threadIdx.x;
    lsh[i] = cap_len[i];
    __syncthreads();
    int li = lsh[i];
    int rank = 0;
    for (int j = 0; j < B; ++j) {
        int lj = lsh[j];
        rank += (lj > li) || (lj == li && j < i);   // stable descending
    }
    sort_ind[rank] = i;
    dec_len[rank]  = li - 1;
}

// ---------------- fp32 -> bf16 convert ----------------
__global__ void convert_kernel(const float* __restrict__ src,
                               __hip_bfloat16* __restrict__ dst, int n) {
    int i = blockIdx.x * 256 + threadIdx.x;
    if (i < n) dst[i] = __float2bfloat16(src[i]);
}

// ---------------- pack W1dyn = [W1_ih[:,0:1024] | W1_hh] -> bf16 (4096 x 2048) ----------------
__global__ void pack_w1dyn_kernel(const float* __restrict__ Wih,
                                  const float* __restrict__ Whh,
                                  __hip_bfloat16* __restrict__ dst) {
    int i = blockIdx.x * 256 + threadIdx.x;
    int n = i >> 11, k = i & 2047;
    float v = (k < 1024) ? Wih[(size_t)n * 4096 + k] : Whh[(size_t)n * 1024 + (k - 1024)];
    dst[i] = __float2bfloat16(v);
}

// ---------------- pack W1fm = W1_ih[:,1024:3072] -> bf16 (4096 x 2048) ----------------
__global__ void pack_w1fm_kernel(const float* __restrict__ Wih,
                                 __hip_bfloat16* __restrict__ dst) {
    int i = blockIdx.x * 256 + threadIdx.x;
    int n = i >> 11, k = i & 2047;
    dst[i] = __float2bfloat16(Wih[(size_t)n * 4096 + 1024 + k]);
}

// ---------------- pack W1emb = W1_ih[:,3072:4096] -> bf16 (4096 x 1024) ----------------
__global__ void pack_w1emb_kernel(const float* __restrict__ Wih,
                                  __hip_bfloat16* __restrict__ dst) {
    int i = blockIdx.x * 256 + threadIdx.x;
    int n = i >> 10, k = i & 1023;
    dst[i] = __float2bfloat16(Wih[(size_t)n * 4096 + 3072 + k]);
}

// ---------------- pack [W2_ih | W2_hh] -> bf16 (4096 x 4096) ----------------
__global__ void pack_w2_kernel(const float* __restrict__ Wih,
                               const float* __restrict__ Whh,
                               __hip_bfloat16* __restrict__ dst) {
    int i = blockIdx.x * 256 + threadIdx.x;
    int n = i >> 12, k = i & 4095;
    float v = (k < 3072) ? Wih[(size_t)n * 3072 + k] : Whh[(size_t)n * 1024 + (k - 3072)];
    dst[i] = __float2bfloat16(v);
}

// ---------------- sorted feats -> bf16 ----------------
__global__ void feats_bf_kernel(const float* __restrict__ img,
                                const int* __restrict__ sort_ind,
                                __hip_bfloat16* __restrict__ dst) {
    int i = blockIdx.x * 256 + threadIdx.x;
    int b = i / (NN * FF);
    int r = i % (NN * FF);
    dst[i] = __float2bfloat16(img[(size_t)sort_ind[b] * (NN * FF) + r]);
}

// ---------------- feats_mean -> fmbf (128 x 2048 bf16) ----------------
__global__ void fm_kernel(const float* __restrict__ img,
                          const int* __restrict__ sort_ind,
                          __hip_bfloat16* __restrict__ fmbf) {
    int i = blockIdx.x * 256 + threadIdx.x;
    int b = i >> 11;
    int f = i & 2047;
    const float* src = img + (size_t)sort_ind[b] * (NN * FF) + f;
    float s = 0.f;
#pragma unroll
    for (int n = 0; n < NN; ++n) s += src[n * FF];
    fmbf[i] = __float2bfloat16(s * (1.0f / NN));
}

// ---------------- embcat gather: row t*128+b = emb[caps[sorted_b][t]] (2432 x 1024 bf16) ----
__global__ void embcat_kernel(const float* __restrict__ emb,
                              const int* __restrict__ caps,
                              const int* __restrict__ sort_ind,
                              __hip_bfloat16* __restrict__ embcat) {
    int i = blockIdx.x * 256 + threadIdx.x;   // TT*B*EE threads
    int row = i >> 10;
    int e = i & 1023;
    int t = row >> 7;       // row = t*128 + b
    int b = row & 127;
    int cap = caps[sort_ind[b] * LL + t];
    embcat[i] = __float2bfloat16(emb[(size_t)cap * EE + e]);
}

// ---------------- bf16 MFMA GEMM core ----------------
// EPI=0: fp32 partial at C. EPI=2: bf16 output (att1).
// EPI=3: batched preds epilogue: row = t*128+b; mask by (t < dec_len[b]); +bias; N guard.
#define BM 128
#define BN 64
#define BK 64
#define LDS_K 72

template<int EPI>
__device__ __forceinline__ void gemm_core(
        short (*As)[LDS_K], short (*Wsm)[LDS_K],
        int bm, int bn, int k0,
        const __hip_bfloat16* __restrict__ A, int lda,
        const __hip_bfloat16* __restrict__ W, int ldw,
        float* __restrict__ C, int ldc,
        int N, int Kc,
        const float* __restrict__ bias,
        const int* __restrict__ dec_len) {
    const int tid  = threadIdx.x;
    const int lane = tid & 63;
    const int wv   = tid >> 6;
    const int quad = lane >> 4;
    const int l15  = lane & 15;
    const int wm   = (wv >> 1) * 64;
    const int wn   = (wv & 1) * 32;
    const int srow = tid >> 3;
    const int scol = (tid & 7) * 8;

    floatx4 acc[4][2];
#pragma unroll
    for (int i = 0; i < 4; ++i)
#pragma unroll
        for (int j = 0; j < 2; ++j)
            acc[i][j] = (floatx4){0.f, 0.f, 0.f, 0.f};

    const __hip_bfloat16* Aptr = A + (size_t)(bm + srow) * lda + k0 + scol;
    const __hip_bfloat16* Wptr = W + k0 + scol;

    for (int kt = 0; kt < Kc; kt += BK) {
#pragma unroll
        for (int p = 0; p < 4; ++p) {
            floatx4 v = *(const floatx4*)(Aptr + (size_t)(p * 32) * lda + kt);
            *(floatx4*)(&As[p * 32 + srow][scol]) = v;
        }
#pragma unroll
        for (int p = 0; p < 2; ++p) {
            int gw = bn + p * 32 + srow;
            floatx4 v;
            if (EPI != 3 || gw < N)
                v = *(const floatx4*)(Wptr + (size_t)gw * ldw + kt);
            else
                v = (floatx4){0.f, 0.f, 0.f, 0.f};
            *(floatx4*)(&Wsm[p * 32 + srow][scol]) = v;
        }
        __syncthreads();
#pragma unroll
        for (int ks = 0; ks < 2; ++ks) {
            short8 af[4], bw[2];
#pragma unroll
            for (int i = 0; i < 4; ++i)
                af[i] = *(const short8*)(&As[wm + i * 16 + l15][ks * 32 + quad * 8]);
#pragma unroll
            for (int j = 0; j < 2; ++j)
                bw[j] = *(const short8*)(&Wsm[wn + j * 16 + l15][ks * 32 + quad * 8]);
#pragma unroll
            for (int i = 0; i < 4; ++i)
#pragma unroll
                for (int j = 0; j < 2; ++j)
                    acc[i][j] = __builtin_amdgcn_mfma_f32_16x16x32_bf16(
                        af[i], bw[j], acc[i][j], 0, 0, 0);
        }
        __syncthreads();
    }

    // D layout: row = quad*4+reg, col = lane&15 (m89-verified)
#pragma unroll
    for (int i = 0; i < 4; ++i) {
        int m = bm + wm + i * 16 + quad * 4;
#pragma unroll
        for (int j = 0; j < 2; ++j) {
            int n = bn + wn + j * 16 + l15;
            if (EPI == 3 && n >= N) continue;
#pragma unroll
            for (int r = 0; r < 4; ++r) {
                float v = acc[i][j][r];
                if (EPI == 3) {
                    int row = m + r;
                    int tt = row >> 7;          // row = t*128 + b
                    int bb = row & 127;
                    bool act = tt < dec_len[bb];
                    C[(size_t)bb * (TT * VV) + (size_t)tt * VV + n] =
                        act ? (v + bias[n]) : 0.f;
                } else if (EPI == 2) {
                    ((__hip_bfloat16*)C)[(size_t)(m + r) * ldc + n] = __float2bfloat16(v);
                } else {
                    C[(size_t)(m + r) * ldc + n] = v;
                }
            }
        }
    }
}

// ---------------- standalone GEMM wrapper ----------------
template<int EPI>
__global__ __launch_bounds__(256) void gemm_bf16(
        const __hip_bfloat16* __restrict__ A, int lda,
        const __hip_bfloat16* __restrict__ W, int ldw,
        float* __restrict__ C, int ldc, size_t pstride,
        int N, int Kc,
        const float* __restrict__ bias,
        const int* __restrict__ dec_len) {
    __shared__ __align__(16) short As[BM][LDS_K];
    __shared__ __align__(16) short Wsm[BN][LDS_K];
    gemm_core<EPI>(As, Wsm, blockIdx.y * BM, blockIdx.x * BN, blockIdx.z * Kc,
                   A, lda, W, ldw, C + (size_t)blockIdx.z * pstride, ldc,
                   N, Kc, bias, dec_len);
}

// ---------------- D3: att2 (h1@Wd^T, split8) + g2h ([h1|h2]@W2[:,2048:]^T, split4) ----------
// Both depend only on h1/h2; merging removes a boundary and pulls g2's h-half off the
// post-attention critical path.
__global__ __launch_bounds__(256) void gemm_d3(
        const __hip_bfloat16* __restrict__ x2full,
        const __hip_bfloat16* __restrict__ Wd_bf,
        const __hip_bfloat16* __restrict__ W2cat,
        float* __restrict__ att2_part, size_t astride,
        float* __restrict__ g_part, size_t gstride) {
    __shared__ __align__(16) short As[BM][LDS_K];
    __shared__ __align__(16) short Wsm[BN][LDS_K];
    int idx = blockIdx.x;
    if (idx < 128) {            // att2: 16 n-blocks x 8 z, Kc=128
        int bx = idx & 15, z = idx >> 4;
        gemm_core<0>(As, Wsm, 0, bx * BN, z * 128,
                     x2full + 2048, 4096, Wd_bf, DD,
                     att2_part + (size_t)z * astride, AA,
                     AA, 128, nullptr, nullptr);
    } else {                    // g2h: 64 n-blocks x 4 z, Kc=512, K offset 2048
        int j = idx - 128;
        int bx = j & 63, z = j >> 6;
        gemm_core<0>(As, Wsm, 0, bx * BN, 2048 + z * 512,
                     x2full, 4096, W2cat, 4096,
                     g_part + (size_t)(4 + z) * gstride, 4096,
                     4096, 512, nullptr, nullptr);
    }
}

// ---------------- LSTM pointwise: NZ split-K partials + optional fp32 pre-terms ----------
// pre0/pre1: precomputed gate contributions (fm / emb_t), layout b*4096 + gate*1024 + d.
// hs3: optional bf16 h history (stride 1024) for batched preds.
template<int NZ>
__global__ void lstm_kernel(const float* __restrict__ gpart, size_t pstride,
                            const float* __restrict__ bih, const float* __restrict__ bhh,
                            const float* __restrict__ pre0, const float* __restrict__ pre1,
                            float* __restrict__ c,
                            __hip_bfloat16* __restrict__ hs1, int st1,
                            __hip_bfloat16* __restrict__ hs2, int st2,
                            __hip_bfloat16* __restrict__ hs3,
                            const int* __restrict__ dec_len, int t) {
    int idx = blockIdx.x * 256 + threadIdx.x;   // B*DD threads
    int b = idx >> 10;
    int d = idx & 1023;
    if (t >= dec_len[b]) return;                 // inactive: freeze h,c
    float g[4];
#pragma unroll
    for (int gate = 0; gate < 4; ++gate) {
        size_t o = (size_t)b * 4096 + gate * 1024 + d;
        float s = bih[gate * 1024 + d] + bhh[gate * 1024 + d];
        if (pre0) s += pre0[o];
        if (pre1) s += pre1[o];
#pragma unroll
        for (int z = 0; z < NZ; ++z) s += gpart[z * pstride + o];
        g[gate] = s;
    }
    float si = 1.f / (1.f + expf(-g[0]));
    float sf = 1.f / (1.f + expf(-g[1]));
    float so = 1.f / (1.f + expf(-g[3]));
    float cc = sf * c[idx] + si * tanhf(g[2]);
    float hh = so * tanhf(cc);
    c[idx] = cc;
    __hip_bfloat16 hb = __float2bfloat16(hh);
    hs1[(size_t)b * st1 + d] = hb;
    hs2[(size_t)b * st2 + d] = hb;
    if (hs3) hs3[(size_t)b * 1024 + d] = hb;
}

// ---------------- fused attention: av-reduce + score + softmax + awe (block per b) -------
__global__ __launch_bounds__(256) void att_fused(
        const float* __restrict__ p, size_t pstride,   // 8 x (B,AA) partials
        const float* __restrict__ bf_,
        const float* __restrict__ bd_,
        float* __restrict__ av_g,                      // (B,AA) scratch
        const __hip_bfloat16* __restrict__ att1,       // (B*NN, AA) bf16
        const float* __restrict__ Wa,                  // (AA)
        const __hip_bfloat16* __restrict__ feats,      // (B, NN, FF) sorted bf16
        __hip_bfloat16* __restrict__ x2full) {         // awe slot, row stride 4096
    int b = blockIdx.x;
    int tid = threadIdx.x;
    __shared__ float esh[NN];
    __shared__ float alpha[NN];

    // phase 1: av = bf + bd + sum_z partials  (coalesced, 4 elems/thread)
#pragma unroll
    for (int rep = 0; rep < 4; ++rep) {
        int a = rep * 256 + tid;
        size_t o = (size_t)b * AA + a;
        float s = bf_[a] + bd_[a];
#pragma unroll
        for (int z = 0; z < 8; ++z) s += p[z * pstride + o];
        av_g[o] = s;
    }
    __syncthreads();

    // phase 2: scores, wave per n (4 waves, 9 n each)
    int wv = tid >> 6, lane = tid & 63;
    const float* avp = av_g + (size_t)b * AA + lane * 16;
    const float* wap = Wa + lane * 16;
    for (int n = wv; n < NN; n += 4) {
        const __hip_bfloat16* a1 = att1 + ((size_t)b * NN + n) * AA + lane * 16;
        float pacc = 0.f;
#pragma unroll
        for (int h = 0; h < 2; ++h) {
            short8 a8 = *(const short8*)(a1 + h * 8);
            floatx4 v0 = *(const floatx4*)(avp + h * 8);
            floatx4 v1 = *(const floatx4*)(avp + h * 8 + 4);
            floatx4 w0 = *(const floatx4*)(wap + h * 8);
            floatx4 w1 = *(const floatx4*)(wap + h * 8 + 4);
            float af[8];
#pragma unroll
            for (int q = 0; q < 8; ++q) {
                union { short s; __hip_bfloat16 b; } u; u.s = a8[q];
                af[q] = __bfloat162float(u.b);
            }
#pragma unroll
            for (int q = 0; q < 4; ++q) {
                pacc += fmaxf(af[q] + v0[q], 0.f) * w0[q];
                pacc += fmaxf(af[4 + q] + v1[q], 0.f) * w1[q];
            }
        }
        for (int off = 32; off; off >>= 1) pacc += __shfl_down(pacc, off);
        if (lane == 0) esh[n] = pacc;
    }
    __syncthreads();

    // phase 3: softmax over NN=36 on wave 0
    if (tid < 64) {
        float ev = (tid < NN) ? esh[tid] : -INFINITY;
        float m = ev;
        for (int off = 32; off; off >>= 1) m = fmaxf(m, __shfl_down(m, off));
        m = __shfl(m, 0);
        float ex = (tid < NN) ? expf(ev - m) : 0.f;
        float s = ex;
        for (int off = 32; off; off >>= 1) s += __shfl_down(s, off);
        s = __shfl(s, 0);
        if (tid < NN) alpha[tid] = ex / s;
    }
    __syncthreads();

    // phase 4: awe — 8 outputs/thread (256*8 = 2048), coalesced 16B/lane
    const __hip_bfloat16* src = feats + (size_t)b * (NN * FF) + tid * 8;
    float s[8] = {0.f, 0.f, 0.f, 0.f, 0.f, 0.f, 0.f, 0.f};
#pragma unroll
    for (int n = 0; n < NN; ++n) {
        short8 v = *(const short8*)(src + (size_t)n * FF);
        float al = alpha[n];
#pragma unroll
        for (int q = 0; q < 8; ++q) {
            union { short s_; __hip_bfloat16 b_; } u; u.s_ = v[q];
            s[q] += al * __bfloat162float(u.b_);
        }
    }
    short8 o8;
#pragma unroll
    for (int q = 0; q < 8; ++q) {
        union { short s_; __hip_bfloat16 b_; } u; u.b_ = __float2bfloat16(s[q]);
        o8[q] = u.s_;
    }
    *(short8*)(x2full + (size_t)b * 4096 + tid * 8) = o8;
}

// ---------------- host launcher ----------------
extern "C" void kernel_launch(void* const* d_in, const int* in_sizes, int n_in,
                              void* d_out, int out_size, void* d_ws, size_t ws_size,
                              hipStream_t stream) {
    const float* img     = (const float*)d_in[0];
    const int*   caps    = (const int*)d_in[1];
    const int*   cap_len = (const int*)d_in[2];
    const float* emb     = (const float*)d_in[3];
    const float* W1_ih   = (const float*)d_in[4];
    const float* W1_hh   = (const float*)d_in[5];
    const float* b1_ih   = (const float*)d_in[6];
    const float* b1_hh   = (const float*)d_in[7];
    const float* W2_ih   = (const float*)d_in[8];
    const float* W2_hh   = (const float*)d_in[9];
    const float* b2_ih   = (const float*)d_in[10];
    const float* b2_hh   = (const float*)d_in[11];
    const float* Wf      = (const float*)d_in[12];
    const float* bf      = (const float*)d_in[13];
    const float* Wd      = (const float*)d_in[14];
    const float* bd      = (const float*)d_in[15];
    const float* Wa      = (const float*)d_in[16];
    // d_in[17] = ba: softmax shift-invariant, unused
    const float* Wfc     = (const float*)d_in[18];
    const float* bfc     = (const float*)d_in[19];
    float* out = (float*)d_out;
    (void)in_sizes; (void)n_in; (void)out_size; (void)ws_size;

    char* ws = (char*)d_ws;
    size_t off = 0;
    auto alloc = [&](size_t bytes) -> void* {
        void* p = ws + off;
        off += (bytes + 255) & ~(size_t)255;
        return p;
    };
    int* sort_ind = (int*)alloc(B * sizeof(int));
    int* dec_len  = (int*)alloc(B * sizeof(int));
    __hip_bfloat16* W1dyn    = (__hip_bfloat16*)alloc((size_t)4096 * 2048 * 2);
    __hip_bfloat16* W1fm     = (__hip_bfloat16*)alloc((size_t)4096 * 2048 * 2);
    __hip_bfloat16* W1emb    = (__hip_bfloat16*)alloc((size_t)4096 * 1024 * 2);
    __hip_bfloat16* W2cat    = (__hip_bfloat16*)alloc((size_t)4096 * 4096 * 2);
    __hip_bfloat16* Wd_bf    = (__hip_bfloat16*)alloc((size_t)AA * DD * 2);
    __hip_bfloat16* Wfc_bf   = (__hip_bfloat16*)alloc((size_t)VV * DD * 2);
    __hip_bfloat16* Wf_bf    = (__hip_bfloat16*)alloc((size_t)AA * FF * 2);
    __hip_bfloat16* feats_bf = (__hip_bfloat16*)alloc((size_t)B * NN * FF * 2);
    __hip_bfloat16* att1_bf  = (__hip_bfloat16*)alloc((size_t)B * NN * AA * 2);
    __hip_bfloat16* fmbf     = (__hip_bfloat16*)alloc((size_t)B * 2048 * 2);
    __hip_bfloat16* embcat   = (__hip_bfloat16*)alloc((size_t)TT * B * EE * 2);
    __hip_bfloat16* h2hist   = (__hip_bfloat16*)alloc((size_t)TT * B * DD * 2);
    float* gpre_fm   = (float*)alloc((size_t)B * 4096 * 4);
    float* gpre_emb  = (float*)alloc((size_t)TT * B * 4096 * 4);
    float* g_part    = (float*)alloc((size_t)8 * B * 4096 * 4);
    float* att2_part = (float*)alloc((size_t)8 * B * AA * 4);
    float* av        = (float*)alloc((size_t)B * AA * 4);
    __hip_bfloat16* x1dyn  = (__hip_bfloat16*)alloc((size_t)B * 2048 * 2); // [h2|h1]
    __hip_bfloat16* x2full = (__hip_bfloat16*)alloc((size_t)B * 4096 * 2); // [awe|h1|h2]
    float* c1 = (float*)alloc((size_t)B * DD * 4);
    float* c2 = (float*)alloc((size_t)B * DD * 4);

    const size_t gstride = (size_t)B * 4096;
    const size_t astride = (size_t)B * AA;

    // ---- setup ----
    sort_kernel<<<1, B, 0, stream>>>(cap_len, sort_ind, dec_len);
    pack_w1dyn_kernel<<<(4096 * 2048) / 256, 256, 0, stream>>>(W1_ih, W1_hh, W1dyn);
    pack_w1fm_kernel<<<(4096 * 2048) / 256, 256, 0, stream>>>(W1_ih, W1fm);
    pack_w1emb_kernel<<<(4096 * 1024) / 256, 256, 0, stream>>>(W1_ih, W1emb);
    pack_w2_kernel<<<(4096 * 4096) / 256, 256, 0, stream>>>(W2_ih, W2_hh, W2cat);
    convert_kernel<<<(AA * DD) / 256, 256, 0, stream>>>(Wd, Wd_bf, AA * DD);
    convert_kernel<<<(VV * DD + 255) / 256, 256, 0, stream>>>(Wfc, Wfc_bf, VV * DD);
    convert_kernel<<<(AA * FF) / 256, 256, 0, stream>>>(Wf, Wf_bf, AA * FF);
    feats_bf_kernel<<<(B * NN * FF) / 256, 256, 0, stream>>>(img, sort_ind, feats_bf);
    fm_kernel<<<(B * 2048) / 256, 256, 0, stream>>>(img, sort_ind, fmbf);
    embcat_kernel<<<(TT * B * EE) / 256, 256, 0, stream>>>(emb, caps, sort_ind, embcat);
    hipMemsetAsync(x1dyn, 0, (size_t)B * 2048 * 2, stream);
    hipMemsetAsync(x2full, 0, (size_t)B * 4096 * 2, stream);
    hipMemsetAsync(c1, 0, (size_t)B * DD * 4, stream);
    hipMemsetAsync(c2, 0, (size_t)B * DD * 4, stream);
    hipMemsetAsync(h2hist, 0, (size_t)TT * B * DD * 2, stream);  // poison-proof inactive rows

    // att1 = feats_bf @ Wf^T (bf16 out; bf bias folded into attention av)
    gemm_bf16<2><<<dim3(AA / BN, (B * NN) / BM, 1), 256, 0, stream>>>(
        feats_bf, FF, Wf_bf, FF, (float*)att1_bf, AA, 0, AA, FF, nullptr, nullptr);
    // gpre_fm = fm @ W1fm^T (128 x 4096 fp32)
    gemm_bf16<0><<<dim3(4096 / BN, 1, 1), 256, 0, stream>>>(
        fmbf, 2048, W1fm, 2048, gpre_fm, 4096, 0, 4096, 2048, nullptr, nullptr);
    // gpre_emb = embcat @ W1emb^T (2432 x 4096 fp32), all 19 steps at once
    gemm_bf16<0><<<dim3(4096 / BN, TT, 1), 256, 0, stream>>>(
        embcat, EE, W1emb, EE, gpre_emb, 4096, 0, 4096, EE, nullptr, nullptr);

    for (int t = 0; t < TT; ++t) {
        // D1: g1dyn = [h2|h1] @ W1dyn^T : K=2048, split-K 4 (Kc=512) -> slices 0..3
        gemm_bf16<0><<<dim3(4096 / BN, 1, 4), 256, 0, stream>>>(
            x1dyn, 2048, W1dyn, 2048, g_part, 4096, gstride, 4096, 512,
            nullptr, nullptr);

        // D2: lstm1 = sum(4 partials) + gpre_fm + gpre_emb[t] + biases -> h1
        lstm_kernel<4><<<(B * DD) / 256, 256, 0, stream>>>(
            g_part, gstride, b1_ih, b1_hh,
            gpre_fm, gpre_emb + (size_t)t * B * 4096, c1,
            x1dyn + 1024, 2048, x2full + 2048, 4096, nullptr, dec_len, t);

        // D3: att2 partials (h1@Wd^T, split8) + g2h ([h1|h2]@W2[:,2048:], split4 -> slices 4..7)
        gemm_d3<<<128 + 256, 256, 0, stream>>>(
            x2full, Wd_bf, W2cat, att2_part, astride, g_part, gstride);

        // D4: fused av-reduce + score + softmax + awe
        att_fused<<<B, 256, 0, stream>>>(att2_part, astride, bf, bd, av,
                                         att1_bf, Wa, feats_bf, x2full);

        // D5: g2awe = awe @ W2[:,0:2048]^T : split-K 4 (Kc=512) -> slices 0..3
        gemm_bf16<0><<<dim3(4096 / BN, 1, 4), 256, 0, stream>>>(
            x2full, 4096, W2cat, 4096, g_part, 4096, gstride, 4096, 512,
            nullptr, nullptr);

        // D6: lstm2 = sum(8 partials: awe 0..3 + h 4..7) + biases -> h2 (+h2hist[t])
        lstm_kernel<8><<<(B * DD) / 256, 256, 0, stream>>>(
            g_part, gstride, b2_ih, b2_hh, nullptr, nullptr, c2,
            x1dyn + 0, 2048, x2full + 3072, 4096,
            h2hist + (size_t)t * B * DD, dec_len, t);
    }

    // batched preds for all steps: h2hist (2432 x 1024) @ Wfc^T, masked + bias
    gemm_bf16<3><<<dim3((VV + BN - 1) / BN, TT, 1), 256, 0, stream>>>(
        h2hist, DD, Wfc_bf, DD, out, TT * VV, 0, VV, DD, bfc, dec_len);
}

// Round 6
// 1601.851 us; speedup vs baseline: 5.0512x; 1.0587x over previous
//
#include <hip/hip_runtime.h>
#include <hip/hip_bf16.h>
#include <math.h>

#define B   128
#define NN  36
#define FF  2048
#define AA  1024
#define EE  1024
#define DD  1024
#define VV  10000
#define LL  20
#define TT  19

typedef __attribute__((ext_vector_type(8))) short short8;
typedef __attribute__((ext_vector_type(4))) float floatx4;

// ---------------- sort (stable descending by length) ----------------
__global__ __launch_bounds__(B) void sort_kernel(const int* __restrict__ cap_len,
                                                 int* __restrict__ sort_ind,
                                                 int* __restrict__ dec_len) {
    __shared__ int lsh[B];
    int i = threadIdx.x;
    lsh[i] = cap_len[i];
    __syncthreads();
    int li = lsh[i];
    int rank = 0;
    for (int j = 0; j < B; ++j) {
        int lj = lsh[j];
        rank += (lj > li) || (lj == li && j < i);   // stable descending
    }
    sort_ind[rank] = i;
    dec_len[rank]  = li - 1;
}

// ---------------- one launch for all weight packs/converts + feats gather ----------------
// Segments (cumulative element offsets):
//   [0,        8388608)  W1dyn = [W1_ih[:,0:1024] | W1_hh]      (4096 x 2048)
//   [8388608, 16777216)  W1fm  = W1_ih[:,1024:3072]             (4096 x 2048)
//   [16777216,20971520)  W1emb = W1_ih[:,3072:4096]             (4096 x 1024)
//   [20971520,37748736)  W2cat = [W2_ih | W2_hh]                (4096 x 4096)
//   [37748736,38797312)  Wd_bf                                  (1024 x 1024)
//   [38797312,49037312)  Wfc_bf                                 (10000 x 1024)
//   [49037312,51134464)  Wf_bf                                  (1024 x 2048)
//   [51134464,60571648)  feats_bf (sorted gather)               (128 x 36 x 2048)
__global__ void pack_all_kernel(const float* __restrict__ W1_ih, const float* __restrict__ W1_hh,
                                const float* __restrict__ W2_ih, const float* __restrict__ W2_hh,
                                const float* __restrict__ Wd,    const float* __restrict__ Wfc,
                                const float* __restrict__ Wf,    const float* __restrict__ img,
                                const int* __restrict__ sort_ind,
                                __hip_bfloat16* __restrict__ W1dyn, __hip_bfloat16* __restrict__ W1fm,
                                __hip_bfloat16* __restrict__ W1emb, __hip_bfloat16* __restrict__ W2cat,
                                __hip_bfloat16* __restrict__ Wd_bf, __hip_bfloat16* __restrict__ Wfc_bf,
                                __hip_bfloat16* __restrict__ Wf_bf, __hip_bfloat16* __restrict__ feats_bf) {
    size_t idx = (size_t)blockIdx.x * 256 + threadIdx.x;
    if (idx < 8388608UL) {
        size_t i = idx; int n = i >> 11, k = i & 2047;
        float v = (k < 1024) ? W1_ih[(size_t)n * 4096 + k] : W1_hh[(size_t)n * 1024 + (k - 1024)];
        W1dyn[i] = __float2bfloat16(v);
    } else if (idx < 16777216UL) {
        size_t i = idx - 8388608UL; int n = i >> 11, k = i & 2047;
        W1fm[i] = __float2bfloat16(W1_ih[(size_t)n * 4096 + 1024 + k]);
    } else if (idx < 20971520UL) {
        size_t i = idx - 16777216UL; int n = i >> 10, k = i & 1023;
        W1emb[i] = __float2bfloat16(W1_ih[(size_t)n * 4096 + 3072 + k]);
    } else if (idx < 37748736UL) {
        size_t i = idx - 20971520UL; int n = i >> 12, k = i & 4095;
        float v = (k < 3072) ? W2_ih[(size_t)n * 3072 + k] : W2_hh[(size_t)n * 1024 + (k - 3072)];
        W2cat[i] = __float2bfloat16(v);
    } else if (idx < 38797312UL) {
        size_t i = idx - 37748736UL;
        Wd_bf[i] = __float2bfloat16(Wd[i]);
    } else if (idx < 49037312UL) {
        size_t i = idx - 38797312UL;
        Wfc_bf[i] = __float2bfloat16(Wfc[i]);
    } else if (idx < 51134464UL) {
        size_t i = idx - 49037312UL;
        Wf_bf[i] = __float2bfloat16(Wf[i]);
    } else {
        size_t i = idx - 51134464UL;
        int b = (int)(i / (NN * FF));
        int r = (int)(i % (NN * FF));
        feats_bf[i] = __float2bfloat16(img[(size_t)sort_ind[b] * (NN * FF) + r]);
    }
}

// ---------------- feats_mean -> fmbf (128 x 2048 bf16) ----------------
__global__ void fm_kernel(const float* __restrict__ img,
                          const int* __restrict__ sort_ind,
                          __hip_bfloat16* __restrict__ fmbf) {
    int i = blockIdx.x * 256 + threadIdx.x;
    int b = i >> 11;
    int f = i & 2047;
    const float* src = img + (size_t)sort_ind[b] * (NN * FF) + f;
    float s = 0.f;
#pragma unroll
    for (int n = 0; n < NN; ++n) s += src[n * FF];
    fmbf[i] = __float2bfloat16(s * (1.0f / NN));
}

// ---------------- embcat gather: row t*128+b = emb[caps[sorted_b][t]] (2432 x 1024 bf16) ----
__global__ void embcat_kernel(const float* __restrict__ emb,
                              const int* __restrict__ caps,
                              const int* __restrict__ sort_ind,
                              __hip_bfloat16* __restrict__ embcat) {
    int i = blockIdx.x * 256 + threadIdx.x;   // TT*B*EE threads
    int row = i >> 10;
    int e = i & 1023;
    int t = row >> 7;       // row = t*128 + b
    int b = row & 127;
    int cap = caps[sort_ind[b] * LL + t];
    embcat[i] = __float2bfloat16(emb[(size_t)cap * EE + e]);
}

// ---------------- bf16 MFMA GEMM core ----------------
// EPI=0: fp32 partial at C. EPI=2: bf16 output (att1).
// EPI=3: batched preds epilogue: row = t*128+b; mask by (t < dec_len[b]); +bias; N guard.
#define BM 128
#define BN 64
#define BK 64
#define LDS_K 72

template<int EPI>
__device__ __forceinline__ void gemm_core(
        short (*As)[LDS_K], short (*Wsm)[LDS_K],
        int bm, int bn, int k0,
        const __hip_bfloat16* __restrict__ A, int lda,
        const __hip_bfloat16* __restrict__ W, int ldw,
        float* __restrict__ C, int ldc,
        int N, int Kc,
        const float* __restrict__ bias,
        const int* __restrict__ dec_len) {
    const int tid  = threadIdx.x;
    const int lane = tid & 63;
    const int wv   = tid >> 6;
    const int quad = lane >> 4;
    const int l15  = lane & 15;
    const int wm   = (wv >> 1) * 64;
    const int wn   = (wv & 1) * 32;
    const int srow = tid >> 3;
    const int scol = (tid & 7) * 8;

    floatx4 acc[4][2];
#pragma unroll
    for (int i = 0; i < 4; ++i)
#pragma unroll
        for (int j = 0; j < 2; ++j)
            acc[i][j] = (floatx4){0.f, 0.f, 0.f, 0.f};

    const __hip_bfloat16* Aptr = A + (size_t)(bm + srow) * lda + k0 + scol;
    const __hip_bfloat16* Wptr = W + k0 + scol;

    for (int kt = 0; kt < Kc; kt += BK) {
#pragma unroll
        for (int p = 0; p < 4; ++p) {
            floatx4 v = *(const floatx4*)(Aptr + (size_t)(p * 32) * lda + kt);
            *(floatx4*)(&As[p * 32 + srow][scol]) = v;
        }
#pragma unroll
        for (int p = 0; p < 2; ++p) {
            int gw = bn + p * 32 + srow;
            floatx4 v;
            if (EPI != 3 || gw < N)
                v = *(const floatx4*)(Wptr + (size_t)gw * ldw + kt);
            else
                v = (floatx4){0.f, 0.f, 0.f, 0.f};
            *(floatx4*)(&Wsm[p * 32 + srow][scol]) = v;
        }
        __syncthreads();
#pragma unroll
        for (int ks = 0; ks < 2; ++ks) {
            short8 af[4], bw[2];
#pragma unroll
            for (int i = 0; i < 4; ++i)
                af[i] = *(const short8*)(&As[wm + i * 16 + l15][ks * 32 + quad * 8]);
#pragma unroll
            for (int j = 0; j < 2; ++j)
                bw[j] = *(const short8*)(&Wsm[wn + j * 16 + l15][ks * 32 + quad * 8]);
#pragma unroll
            for (int i = 0; i < 4; ++i)
#pragma unroll
                for (int j = 0; j < 2; ++j)
                    acc[i][j] = __builtin_amdgcn_mfma_f32_16x16x32_bf16(
                        af[i], bw[j], acc[i][j], 0, 0, 0);
        }
        __syncthreads();
    }

    // D layout: row = quad*4+reg, col = lane&15 (m89-verified)
#pragma unroll
    for (int i = 0; i < 4; ++i) {
        int m = bm + wm + i * 16 + quad * 4;
#pragma unroll
        for (int j = 0; j < 2; ++j) {
            int n = bn + wn + j * 16 + l15;
            if (EPI == 3 && n >= N) continue;
#pragma unroll
            for (int r = 0; r < 4; ++r) {
                float v = acc[i][j][r];
                if (EPI == 3) {
                    int row = m + r;
                    int tt = row >> 7;          // row = t*128 + b
                    int bb = row & 127;
                    bool act = tt < dec_len[bb];
                    C[(size_t)bb * (TT * VV) + (size_t)tt * VV + n] =
                        act ? (v + bias[n]) : 0.f;
                } else if (EPI == 2) {
                    ((__hip_bfloat16*)C)[(size_t)(m + r) * ldc + n] = __float2bfloat16(v);
                } else {
                    C[(size_t)(m + r) * ldc + n] = v;
                }
            }
        }
    }
}

// ---------------- standalone GEMM wrapper ----------------
// grid.x may be padded (e.g. to a multiple of 8 for XCD-stable L2 residency);
// blocks with bx*BN >= N are pure padding and exit immediately.
template<int EPI>
__global__ __launch_bounds__(256) void gemm_bf16(
        const __hip_bfloat16* __restrict__ A, int lda,
        const __hip_bfloat16* __restrict__ W, int ldw,
        float* __restrict__ C, int ldc, size_t pstride,
        int N, int Kc,
        const float* __restrict__ bias,
        const int* __restrict__ dec_len) {
    if (blockIdx.x * BN >= N) return;           // grid padding guard
    __shared__ __align__(16) short As[BM][LDS_K];
    __shared__ __align__(16) short Wsm[BN][LDS_K];
    gemm_core<EPI>(As, Wsm, blockIdx.y * BM, blockIdx.x * BN, blockIdx.z * Kc,
                   A, lda, W, ldw, C + (size_t)blockIdx.z * pstride, ldc,
                   N, Kc, bias, dec_len);
}

// ---------------- D3: att2 (h1@Wd^T, split8) + g2h ([h1|h2]@W2[:,2048:]^T, split4) ----------
__global__ __launch_bounds__(256) void gemm_d3(
        const __hip_bfloat16* __restrict__ x2full,
        const __hip_bfloat16* __restrict__ Wd_bf,
        const __hip_bfloat16* __restrict__ W2cat,
        float* __restrict__ att2_part, size_t astride,
        float* __restrict__ g_part, size_t gstride) {
    __shared__ __align__(16) short As[BM][LDS_K];
    __shared__ __align__(16) short Wsm[BN][LDS_K];
    int idx = blockIdx.x;
    if (idx < 128) {            // att2: 16 n-blocks x 8 z, Kc=128
        int bx = idx & 15, z = idx >> 4;
        gemm_core<0>(As, Wsm, 0, bx * BN, z * 128,
                     x2full + 2048, 4096, Wd_bf, DD,
                     att2_part + (size_t)z * astride, AA,
                     AA, 128, nullptr, nullptr);
    } else {                    // g2h: 64 n-blocks x 4 z, Kc=512, K offset 2048
        int j = idx - 128;
        int bx = j & 63, z = j >> 6;
        gemm_core<0>(As, Wsm, 0, bx * BN, 2048 + z * 512,
                     x2full, 4096, W2cat, 4096,
                     g_part + (size_t)(4 + z) * gstride, 4096,
                     4096, 512, nullptr, nullptr);
    }
}

// ---------------- LSTM pointwise: NZ split-K partials + optional fp32 pre-terms ----------
template<int NZ>
__global__ void lstm_kernel(const float* __restrict__ gpart, size_t pstride,
                            const float* __restrict__ bih, const float* __restrict__ bhh,
                            const float* __restrict__ pre0, const float* __restrict__ pre1,
                            float* __restrict__ c,
                            __hip_bfloat16* __restrict__ hs1, int st1,
                            __hip_bfloat16* __restrict__ hs2, int st2,
                            __hip_bfloat16* __restrict__ hs3,
                            const int* __restrict__ dec_len, int t) {
    int idx = blockIdx.x * 256 + threadIdx.x;   // B*DD threads
    int b = idx >> 10;
    int d = idx & 1023;
    if (t >= dec_len[b]) return;                 // inactive: freeze h,c
    float g[4];
#pragma unroll
    for (int gate = 0; gate < 4; ++gate) {
        size_t o = (size_t)b * 4096 + gate * 1024 + d;
        float s = bih[gate * 1024 + d] + bhh[gate * 1024 + d];
        if (pre0) s += pre0[o];
        if (pre1) s += pre1[o];
#pragma unroll
        for (int z = 0; z < NZ; ++z) s += gpart[z * pstride + o];
        g[gate] = s;
    }
    float si = 1.f / (1.f + expf(-g[0]));
    float sf = 1.f / (1.f + expf(-g[1]));
    float so = 1.f / (1.f + expf(-g[3]));
    float cc = sf * c[idx] + si * tanhf(g[2]);
    float hh = so * tanhf(cc);
    c[idx] = cc;
    __hip_bfloat16 hb = __float2bfloat16(hh);
    hs1[(size_t)b * st1 + d] = hb;
    hs2[(size_t)b * st2 + d] = hb;
    if (hs3) hs3[(size_t)b * 1024 + d] = hb;
}

// ---------------- fused attention: av-reduce + score + softmax + awe (block per b) -------
// 1024 threads: av 1 elem/thread, score 16 waves (2.25 rounds), awe 2 cols/thread.
// Per-element arithmetic order identical to the 256-thread version (bit-identical output).
__global__ __launch_bounds__(1024) void att_fused(
        const float* __restrict__ p, size_t pstride,   // 8 x (B,AA) partials
        const float* __restrict__ bf_,
        const float* __restrict__ bd_,
        float* __restrict__ av_g,                      // (B,AA) scratch
        const __hip_bfloat16* __restrict__ att1,       // (B*NN, AA) bf16
        const float* __restrict__ Wa,                  // (AA)
        const __hip_bfloat16* __restrict__ feats,      // (B, NN, FF) sorted bf16
        __hip_bfloat16* __restrict__ x2full) {         // awe slot, row stride 4096
    int b = blockIdx.x;
    int tid = threadIdx.x;
    __shared__ float esh[NN];
    __shared__ float alpha[NN];

    // phase 1: av = bf + bd + sum_z partials (1 elem/thread, coalesced)
    {
        size_t o = (size_t)b * AA + tid;
        float s = bf_[tid] + bd_[tid];
#pragma unroll
        for (int z = 0; z < 8; ++z) s += p[z * pstride + o];
        av_g[o] = s;
    }
    __syncthreads();

    // phase 2: scores, wave per n (16 waves)
    int wv = tid >> 6, lane = tid & 63;
    const float* avp = av_g + (size_t)b * AA + lane * 16;
    const float* wap = Wa + lane * 16;
    for (int n = wv; n < NN; n += 16) {
        const __hip_bfloat16* a1 = att1 + ((size_t)b * NN + n) * AA + lane * 16;
        float pacc = 0.f;
#pragma unroll
        for (int h = 0; h < 2; ++h) {
            short8 a8 = *(const short8*)(a1 + h * 8);
            floatx4 v0 = *(const floatx4*)(avp + h * 8);
            floatx4 v1 = *(const floatx4*)(avp + h * 8 + 4);
            floatx4 w0 = *(const floatx4*)(wap + h * 8);
            floatx4 w1 = *(const floatx4*)(wap + h * 8 + 4);
            float af[8];
#pragma unroll
            for (int q = 0; q < 8; ++q) {
                union { short s; __hip_bfloat16 b; } u; u.s = a8[q];
                af[q] = __bfloat162float(u.b);
            }
#pragma unroll
            for (int q = 0; q < 4; ++q) {
                pacc += fmaxf(af[q] + v0[q], 0.f) * w0[q];
                pacc += fmaxf(af[4 + q] + v1[q], 0.f) * w1[q];
            }
        }
        for (int off = 32; off; off >>= 1) pacc += __shfl_down(pacc, off);
        if (lane == 0) esh[n] = pacc;
    }
    __syncthreads();

    // phase 3: softmax over NN=36 on wave 0
    if (tid < 64) {
        float ev = (tid < NN) ? esh[tid] : -INFINITY;
        float m = ev;
        for (int off = 32; off; off >>= 1) m = fmaxf(m, __shfl_down(m, off));
        m = __shfl(m, 0);
        float ex = (tid < NN) ? expf(ev - m) : 0.f;
        float s = ex;
        for (int off = 32; off; off >>= 1) s += __shfl_down(s, off);
        s = __shfl(s, 0);
        if (tid < NN) alpha[tid] = ex / s;
    }
    __syncthreads();

    // phase 4: awe — 2 cols/thread (1024*2 = 2048), coalesced 4B/lane
    int f0 = tid * 2;
    const __hip_bfloat16* src = feats + (size_t)b * (NN * FF) + f0;
    float s0 = 0.f, s1 = 0.f;
#pragma unroll
    for (int n = 0; n < NN; ++n) {
        __hip_bfloat162 v = *(const __hip_bfloat162*)(src + n * FF);
        float al = alpha[n];
        s0 += al * __bfloat162float(v.x);
        s1 += al * __bfloat162float(v.y);
    }
    __hip_bfloat162 o;
    o.x = __float2bfloat16(s0);
    o.y = __float2bfloat16(s1);
    *(__hip_bfloat162*)(x2full + (size_t)b * 4096 + f0) = o;
}

// ---------------- host launcher ----------------
extern "C" void kernel_launch(void* const* d_in, const int* in_sizes, int n_in,
                              void* d_out, int out_size, void* d_ws, size_t ws_size,
                              hipStream_t stream) {
    const float* img     = (const float*)d_in[0];
    const int*   caps    = (const int*)d_in[1];
    const int*   cap_len = (const int*)d_in[2];
    const float* emb     = (const float*)d_in[3];
    const float* W1_ih   = (const float*)d_in[4];
    const float* W1_hh   = (const float*)d_in[5];
    const float* b1_ih   = (const float*)d_in[6];
    const float* b1_hh   = (const float*)d_in[7];
    const float* W2_ih   = (const float*)d_in[8];
    const float* W2_hh   = (const float*)d_in[9];
    const float* b2_ih   = (const float*)d_in[10];
    const float* b2_hh   = (const float*)d_in[11];
    const float* Wf      = (const float*)d_in[12];
    const float* bf      = (const float*)d_in[13];
    const float* Wd      = (const float*)d_in[14];
    const float* bd      = (const float*)d_in[15];
    const float* Wa      = (const float*)d_in[16];
    // d_in[17] = ba: softmax shift-invariant, unused
    const float* Wfc     = (const float*)d_in[18];
    const float* bfc     = (const float*)d_in[19];
    float* out = (float*)d_out;
    (void)in_sizes; (void)n_in; (void)out_size; (void)ws_size;

    char* ws = (char*)d_ws;
    size_t off = 0;
    auto alloc = [&](size_t bytes) -> void* {
        void* p = ws + off;
        off += (bytes + 255) & ~(size_t)255;
        return p;
    };
    int* sort_ind = (int*)alloc(B * sizeof(int));
    int* dec_len  = (int*)alloc(B * sizeof(int));
    __hip_bfloat16* W1dyn    = (__hip_bfloat16*)alloc((size_t)4096 * 2048 * 2);
    __hip_bfloat16* W1fm     = (__hip_bfloat16*)alloc((size_t)4096 * 2048 * 2);
    __hip_bfloat16* W1emb    = (__hip_bfloat16*)alloc((size_t)4096 * 1024 * 2);
    __hip_bfloat16* W2cat    = (__hip_bfloat16*)alloc((size_t)4096 * 4096 * 2);
    __hip_bfloat16* Wd_bf    = (__hip_bfloat16*)alloc((size_t)AA * DD * 2);
    __hip_bfloat16* Wfc_bf   = (__hip_bfloat16*)alloc((size_t)VV * DD * 2);
    __hip_bfloat16* Wf_bf    = (__hip_bfloat16*)alloc((size_t)AA * FF * 2);
    __hip_bfloat16* feats_bf = (__hip_bfloat16*)alloc((size_t)B * NN * FF * 2);
    __hip_bfloat16* att1_bf  = (__hip_bfloat16*)alloc((size_t)B * NN * AA * 2);
    __hip_bfloat16* fmbf     = (__hip_bfloat16*)alloc((size_t)B * 2048 * 2);
    __hip_bfloat16* embcat   = (__hip_bfloat16*)alloc((size_t)TT * B * EE * 2);
    __hip_bfloat16* h2hist   = (__hip_bfloat16*)alloc((size_t)TT * B * DD * 2);
    float* gpre_fm   = (float*)alloc((size_t)B * 4096 * 4);
    float* gpre_emb  = (float*)alloc((size_t)TT * B * 4096 * 4);
    float* g_part    = (float*)alloc((size_t)8 * B * 4096 * 4);
    float* att2_part = (float*)alloc((size_t)8 * B * AA * 4);
    float* av        = (float*)alloc((size_t)B * AA * 4);
    __hip_bfloat16* x1dyn  = (__hip_bfloat16*)alloc((size_t)B * 2048 * 2); // [h2|h1]
    __hip_bfloat16* x2full = (__hip_bfloat16*)alloc((size_t)B * 4096 * 2); // [awe|h1|h2]
    float* c1 = (float*)alloc((size_t)B * DD * 4);
    float* c2 = (float*)alloc((size_t)B * DD * 4);

    const size_t gstride = (size_t)B * 4096;
    const size_t astride = (size_t)B * AA;

    // ---- setup ----
    sort_kernel<<<1, B, 0, stream>>>(cap_len, sort_ind, dec_len);
    // all packs/converts + feats gather in ONE launch (60,571,648 threads)
    pack_all_kernel<<<236608, 256, 0, stream>>>(
        W1_ih, W1_hh, W2_ih, W2_hh, Wd, Wfc, Wf, img, sort_ind,
        W1dyn, W1fm, W1emb, W2cat, Wd_bf, Wfc_bf, Wf_bf, feats_bf);
    fm_kernel<<<(B * 2048) / 256, 256, 0, stream>>>(img, sort_ind, fmbf);
    embcat_kernel<<<(TT * B * EE) / 256, 256, 0, stream>>>(emb, caps, sort_ind, embcat);
    hipMemsetAsync(x1dyn, 0, (size_t)B * 2048 * 2, stream);
    hipMemsetAsync(x2full, 0, (size_t)B * 4096 * 2, stream);
    hipMemsetAsync(c1, 0, (size_t)B * DD * 4, stream);
    hipMemsetAsync(c2, 0, (size_t)B * DD * 4, stream);
    hipMemsetAsync(h2hist, 0, (size_t)TT * B * DD * 2, stream);  // poison-proof inactive rows

    // att1 = feats_bf @ Wf^T (bf16 out; bf bias folded into attention av)
    gemm_bf16<2><<<dim3(AA / BN, (B * NN) / BM, 1), 256, 0, stream>>>(
        feats_bf, FF, Wf_bf, FF, (float*)att1_bf, AA, 0, AA, FF, nullptr, nullptr);
    // gpre_fm = fm @ W1fm^T (128 x 4096 fp32)
    gemm_bf16<0><<<dim3(4096 / BN, 1, 1), 256, 0, stream>>>(
        fmbf, 2048, W1fm, 2048, gpre_fm, 4096, 0, 4096, 2048, nullptr, nullptr);
    // gpre_emb = embcat @ W1emb^T (2432 x 4096 fp32), all 19 steps at once
    gemm_bf16<0><<<dim3(4096 / BN, TT, 1), 256, 0, stream>>>(
        embcat, EE, W1emb, EE, gpre_emb, 4096, 0, 4096, EE, nullptr, nullptr);

    for (int t = 0; t < TT; ++t) {
        // D1: g1dyn = [h2|h1] @ W1dyn^T : K=2048, split-K 4 (Kc=512) -> slices 0..3
        gemm_bf16<0><<<dim3(4096 / BN, 1, 4), 256, 0, stream>>>(
            x1dyn, 2048, W1dyn, 2048, g_part, 4096, gstride, 4096, 512,
            nullptr, nullptr);

        // D2: lstm1 = sum(4 partials) + gpre_fm + gpre_emb[t] + biases -> h1
        lstm_kernel<4><<<(B * DD) / 256, 256, 0, stream>>>(
            g_part, gstride, b1_ih, b1_hh,
            gpre_fm, gpre_emb + (size_t)t * B * 4096, c1,
            x1dyn + 1024, 2048, x2full + 2048, 4096, nullptr, dec_len, t);

        // D3: att2 partials (h1@Wd^T, split8) + g2h ([h1|h2]@W2[:,2048:], split4 -> slices 4..7)
        gemm_d3<<<128 + 256, 256, 0, stream>>>(
            x2full, Wd_bf, W2cat, att2_part, astride, g_part, gstride);

        // D4: fused av-reduce + score + softmax + awe (1024 threads/block)
        att_fused<<<B, 1024, 0, stream>>>(att2_part, astride, bf, bd, av,
                                          att1_bf, Wa, feats_bf, x2full);

        // D5: g2awe = awe @ W2[:,0:2048]^T : split-K 4 (Kc=512) -> slices 0..3
        gemm_bf16<0><<<dim3(4096 / BN, 1, 4), 256, 0, stream>>>(
            x2full, 4096, W2cat, 4096, g_part, 4096, gstride, 4096, 512,
            nullptr, nullptr);

        // D6: lstm2 = sum(8 partials: awe 0..3 + h 4..7) + biases -> h2 (+h2hist[t])
        lstm_kernel<8><<<(B * DD) / 256, 256, 0, stream>>>(
            g_part, gstride, b2_ih, b2_hh, nullptr, nullptr, c2,
            x1dyn + 0, 2048, x2full + 3072, 4096,
            h2hist + (size_t)t * B * DD, dec_len, t);
    }

    // batched preds: h2hist (2432 x 1024) @ Wfc^T, masked + bias.
    // grid.x padded 157 -> 160 (multiple of 8 XCDs): each XCD keeps its 20 Wfc
    // panels (2.56 MB) L2-resident across all 19 t-rows instead of re-streaming.
    gemm_bf16<3><<<dim3(160, TT, 1), 256, 0, stream>>>(
        h2hist, DD, Wfc_bf, DD, out, TT * VV, 0, VV, DD, bfc, dec_len);
}

// Round 8
// 1503.133 us; speedup vs baseline: 5.3830x; 1.0657x over previous
//
#include <hip/hip_runtime.h>
#include <hip/hip_bf16.h>
#include <math.h>

#define B   128
#define NN  36
#define FF  2048
#define AA  1024
#define EE  1024
#define DD  1024
#define VV  10000
#define LL  20
#define TT  19

typedef __attribute__((ext_vector_type(8))) short short8;
typedef __attribute__((ext_vector_type(4))) float floatx4;

__device__ __forceinline__ short f2bs(float x) {
    union { __hip_bfloat16 b; short s; } u; u.b = __float2bfloat16(x); return u.s;
}
// convert 8 contiguous fp32 -> 8 bf16 (32B load, 16B store)
__device__ __forceinline__ void cvt8(const float* __restrict__ s, __hip_bfloat16* __restrict__ d) {
    floatx4 a = *(const floatx4*)s;
    floatx4 b = *(const floatx4*)(s + 4);
    short8 o;
    o[0] = f2bs(a[0]); o[1] = f2bs(a[1]); o[2] = f2bs(a[2]); o[3] = f2bs(a[3]);
    o[4] = f2bs(b[0]); o[5] = f2bs(b[1]); o[6] = f2bs(b[2]); o[7] = f2bs(b[3]);
    *(short8*)d = o;
}

// ---------------- sort (stable descending by length) ----------------
__global__ __launch_bounds__(B) void sort_kernel(const int* __restrict__ cap_len,
                                                 int* __restrict__ sort_ind,
                                                 int* __restrict__ dec_len) {
    __shared__ int lsh[B];
    int i = threadIdx.x;
    lsh[i] = cap_len[i];
    __syncthreads();
    int li = lsh[i];
    int rank = 0;
    for (int j = 0; j < B; ++j) {
        int lj = lsh[j];
        rank += (lj > li) || (lj == li && j < i);   // stable descending
    }
    sort_ind[rank] = i;
    dec_len[rank]  = li - 1;
}

// ---------------- one launch for all weight packs/converts + feats gather (8 elems/thread) ----
// Segment element offsets (all multiples of 8; row-splits at 1024/3072 also multiples of 8):
//   [0,        8388608)  W1dyn = [W1_ih[:,0:1024] | W1_hh]      (4096 x 2048)
//   [8388608, 16777216)  W1fm  = W1_ih[:,1024:3072]             (4096 x 2048)
//   [16777216,20971520)  W1emb = W1_ih[:,3072:4096]             (4096 x 1024)
//   [20971520,37748736)  W2cat = [W2_ih | W2_hh]                (4096 x 4096)
//   [37748736,38797312)  Wd_bf                                  (1024 x 1024)
//   [38797312,49037312)  Wfc_bf                                 (10000 x 1024)
//   [49037312,51134464)  Wf_bf                                  (1024 x 2048)
//   [51134464,60571648)  feats_bf (sorted gather)               (128 x 36 x 2048)
__global__ void pack_all_kernel(const float* __restrict__ W1_ih, const float* __restrict__ W1_hh,
                                const float* __restrict__ W2_ih, const float* __restrict__ W2_hh,
                                const float* __restrict__ Wd,    const float* __restrict__ Wfc,
                                const float* __restrict__ Wf,    const float* __restrict__ img,
                                const int* __restrict__ sort_ind,
                                __hip_bfloat16* __restrict__ W1dyn, __hip_bfloat16* __restrict__ W1fm,
                                __hip_bfloat16* __restrict__ W1emb, __hip_bfloat16* __restrict__ W2cat,
                                __hip_bfloat16* __restrict__ Wd_bf, __hip_bfloat16* __restrict__ Wfc_bf,
                                __hip_bfloat16* __restrict__ Wf_bf, __hip_bfloat16* __restrict__ feats_bf) {
    size_t idx = ((size_t)blockIdx.x * 256 + threadIdx.x) * 8;
    const float* src;
    __hip_bfloat16* dst;
    if (idx < 8388608UL) {
        size_t i = idx; int n = (int)(i >> 11), k = (int)(i & 2047);
        src = (k < 1024) ? (W1_ih + (size_t)n * 4096 + k) : (W1_hh + (size_t)n * 1024 + (k - 1024));
        dst = W1dyn + i;
    } else if (idx < 16777216UL) {
        size_t i = idx - 8388608UL; int n = (int)(i >> 11), k = (int)(i & 2047);
        src = W1_ih + (size_t)n * 4096 + 1024 + k;
        dst = W1fm + i;
    } else if (idx < 20971520UL) {
        size_t i = idx - 16777216UL; int n = (int)(i >> 10), k = (int)(i & 1023);
        src = W1_ih + (size_t)n * 4096 + 3072 + k;
        dst = W1emb + i;
    } else if (idx < 37748736UL) {
        size_t i = idx - 20971520UL; int n = (int)(i >> 12), k = (int)(i & 4095);
        src = (k < 3072) ? (W2_ih + (size_t)n * 3072 + k) : (W2_hh + (size_t)n * 1024 + (k - 3072));
        dst = W2cat + i;
    } else if (idx < 38797312UL) {
        size_t i = idx - 37748736UL;
        src = Wd + i;  dst = Wd_bf + i;
    } else if (idx < 49037312UL) {
        size_t i = idx - 38797312UL;
        src = Wfc + i; dst = Wfc_bf + i;
    } else if (idx < 51134464UL) {
        size_t i = idx - 49037312UL;
        src = Wf + i;  dst = Wf_bf + i;
    } else {
        size_t i = idx - 51134464UL;
        int b = (int)(i / (NN * FF));
        int r = (int)(i % (NN * FF));
        src = img + (size_t)sort_ind[b] * (NN * FF) + r;
        dst = feats_bf + i;
    }
    cvt8(src, dst);
}

// ---------------- feats_mean -> fmbf (128 x 2048 bf16), 4 cols/thread ----------------
__global__ void fm_kernel(const float* __restrict__ img,
                          const int* __restrict__ sort_ind,
                          __hip_bfloat16* __restrict__ fmbf) {
    int i = (blockIdx.x * 256 + threadIdx.x) * 4;   // B*2048/4 threads
    int b = i >> 11;
    int f = i & 2047;
    const float* src = img + (size_t)sort_ind[b] * (NN * FF) + f;
    floatx4 s = (floatx4){0.f, 0.f, 0.f, 0.f};
#pragma unroll
    for (int n = 0; n < NN; ++n) {
        floatx4 v = *(const floatx4*)(src + (size_t)n * FF);
        s[0] += v[0]; s[1] += v[1]; s[2] += v[2]; s[3] += v[3];
    }
    short o4[4];
#pragma unroll
    for (int q = 0; q < 4; ++q) o4[q] = f2bs(s[q] * (1.0f / NN));
    *(uint2*)(fmbf + i) = *(uint2*)o4;
}

// ---------------- embcat gather (8 elems/thread): row t*128+b = emb[caps[sorted_b][t]] ----
__global__ void embcat_kernel(const float* __restrict__ emb,
                              const int* __restrict__ caps,
                              const int* __restrict__ sort_ind,
                              __hip_bfloat16* __restrict__ embcat) {
    size_t i = ((size_t)blockIdx.x * 256 + threadIdx.x) * 8;   // TT*B*EE elems
    int row = (int)(i >> 10);
    int e = (int)(i & 1023);
    int t = row >> 7;       // row = t*128 + b
    int b = row & 127;
    int cap = caps[sort_ind[b] * LL + t];
    cvt8(emb + (size_t)cap * EE + e, embcat + i);
}

// ---------------- bf16 MFMA GEMM core ----------------
// EPI=0: fp32 partial at C. EPI=2: bf16 output (att1).
// EPI=3: batched preds epilogue: row = t*128+b; mask by (t < dec_len[b]); +bias; N guard.
#define BM 128
#define BN 64
#define BK 64
#define LDS_K 72

template<int EPI>
__device__ __forceinline__ void gemm_core(
        short (*As)[LDS_K], short (*Wsm)[LDS_K],
        int bm, int bn, int k0,
        const __hip_bfloat16* __restrict__ A, int lda,
        const __hip_bfloat16* __restrict__ W, int ldw,
        float* __restrict__ C, int ldc,
        int N, int Kc,
        const float* __restrict__ bias,
        const int* __restrict__ dec_len) {
    const int tid  = threadIdx.x;
    const int lane = tid & 63;
    const int wv   = tid >> 6;
    const int quad = lane >> 4;
    const int l15  = lane & 15;
    const int wm   = (wv >> 1) * 64;
    const int wn   = (wv & 1) * 32;
    const int srow = tid >> 3;
    const int scol = (tid & 7) * 8;

    floatx4 acc[4][2];
#pragma unroll
    for (int i = 0; i < 4; ++i)
#pragma unroll
        for (int j = 0; j < 2; ++j)
            acc[i][j] = (floatx4){0.f, 0.f, 0.f, 0.f};

    const __hip_bfloat16* Aptr = A + (size_t)(bm + srow) * lda + k0 + scol;
    const __hip_bfloat16* Wptr = W + k0 + scol;

    for (int kt = 0; kt < Kc; kt += BK) {
#pragma unroll
        for (int p = 0; p < 4; ++p) {
            floatx4 v = *(const floatx4*)(Aptr + (size_t)(p * 32) * lda + kt);
            *(floatx4*)(&As[p * 32 + srow][scol]) = v;
        }
#pragma unroll
        for (int p = 0; p < 2; ++p) {
            int gw = bn + p * 32 + srow;
            floatx4 v;
            if (EPI != 3 || gw < N)
                v = *(const floatx4*)(Wptr + (size_t)gw * ldw + kt);
            else
                v = (floatx4){0.f, 0.f, 0.f, 0.f};
            *(floatx4*)(&Wsm[p * 32 + srow][scol]) = v;
        }
        __syncthreads();
#pragma unroll
        for (int ks = 0; ks < 2; ++ks) {
            short8 af[4], bw[2];
#pragma unroll
            for (int i = 0; i < 4; ++i)
                af[i] = *(const short8*)(&As[wm + i * 16 + l15][ks * 32 + quad * 8]);
#pragma unroll
            for (int j = 0; j < 2; ++j)
                bw[j] = *(const short8*)(&Wsm[wn + j * 16 + l15][ks * 32 + quad * 8]);
#pragma unroll
            for (int i = 0; i < 4; ++i)
#pragma unroll
                for (int j = 0; j < 2; ++j)
                    acc[i][j] = __builtin_amdgcn_mfma_f32_16x16x32_bf16(
                        af[i], bw[j], acc[i][j], 0, 0, 0);
        }
        __syncthreads();
    }

    // D layout: row = quad*4+reg, col = lane&15 (m89-verified)
#pragma unroll
    for (int i = 0; i < 4; ++i) {
        int m = bm + wm + i * 16 + quad * 4;
#pragma unroll
        for (int j = 0; j < 2; ++j) {
            int n = bn + wn + j * 16 + l15;
            if (EPI == 3 && n >= N) continue;
#pragma unroll
            for (int r = 0; r < 4; ++r) {
                float v = acc[i][j][r];
                if (EPI == 3) {
                    int row = m + r;
                    int tt = row >> 7;          // row = t*128 + b
                    int bb = row & 127;
                    bool act = tt < dec_len[bb];
                    C[(size_t)bb * (TT * VV) + (size_t)tt * VV + n] =
                        act ? (v + bias[n]) : 0.f;
                } else if (EPI == 2) {
                    ((__hip_bfloat16*)C)[(size_t)(m + r) * ldc + n] = __float2bfloat16(v);
                } else {
                    C[(size_t)(m + r) * ldc + n] = v;
                }
            }
        }
    }
}

// ---------------- standalone GEMM wrapper (grid.x may be XCD-padded) ----------------
template<int EPI>
__global__ __launch_bounds__(256) void gemm_bf16(
        const __hip_bfloat16* __restrict__ A, int lda,
        const __hip_bfloat16* __restrict__ W, int ldw,
        float* __restrict__ C, int ldc, size_t pstride,
        int N, int Kc,
        const float* __restrict__ bias,
        const int* __restrict__ dec_len) {
    if (blockIdx.x * BN >= N) return;           // grid padding guard
    __shared__ __align__(16) short As[BM][LDS_K];
    __shared__ __align__(16) short Wsm[BN][LDS_K];
    gemm_core<EPI>(As, Wsm, blockIdx.y * BM, blockIdx.x * BN, blockIdx.z * Kc,
                   A, lda, W, ldw, C + (size_t)blockIdx.z * pstride, ldc,
                   N, Kc, bias, dec_len);
}

// ---------------- setup GEMMs in one launch: att1 (576) + gpre_emb (1216) + gpre_fm (64) ----
__global__ __launch_bounds__(256) void gemm_setup(
        const __hip_bfloat16* __restrict__ feats_bf, const __hip_bfloat16* __restrict__ Wf_bf,
        __hip_bfloat16* __restrict__ att1_bf,
        const __hip_bfloat16* __restrict__ embcat,   const __hip_bfloat16* __restrict__ W1emb,
        float* __restrict__ gpre_emb,
        const __hip_bfloat16* __restrict__ fmbf,     const __hip_bfloat16* __restrict__ W1fm,
        float* __restrict__ gpre_fm) {
    __shared__ __align__(16) short As[BM][LDS_K];
    __shared__ __align__(16) short Wsm[BN][LDS_K];
    int idx = blockIdx.x;
    if (idx < 576) {            // att1: (36 x 16) tiles, M=4608, N=1024, K=2048
        gemm_core<2>(As, Wsm, (idx >> 4) * BM, (idx & 15) * BN, 0,
                     feats_bf, FF, Wf_bf, FF, (float*)att1_bf, AA,
                     AA, FF, nullptr, nullptr);
    } else if (idx < 1792) {    // gpre_emb: (19 x 64) tiles, M=2432, N=4096, K=1024
        int j = idx - 576;
        gemm_core<0>(As, Wsm, (j >> 6) * BM, (j & 63) * BN, 0,
                     embcat, EE, W1emb, EE, gpre_emb, 4096,
                     4096, EE, nullptr, nullptr);
    } else {                    // gpre_fm: 64 tiles, M=128, N=4096, K=2048
        int j = idx - 1792;
        gemm_core<0>(As, Wsm, 0, j * BN, 0,
                     fmbf, 2048, W1fm, 2048, gpre_fm, 4096,
                     4096, 2048, nullptr, nullptr);
    }
}

// ---------------- D3: att2 (h1@Wd^T, split8) + g2h ([h1|h2]@W2[:,2048:]^T, split4) ----------
__global__ __launch_bounds__(256) void gemm_d3(
        const __hip_bfloat16* __restrict__ x2full,
        const __hip_bfloat16* __restrict__ Wd_bf,
        const __hip_bfloat16* __restrict__ W2cat,
        float* __restrict__ att2_part, size_t astride,
        float* __restrict__ g_part, size_t gstride) {
    __shared__ __align__(16) short As[BM][LDS_K];
    __shared__ __align__(16) short Wsm[BN][LDS_K];
    int idx = blockIdx.x;
    if (idx < 128) {            // att2: 16 n-blocks x 8 z, Kc=128
        int bx = idx & 15, z = idx >> 4;
        gemm_core<0>(As, Wsm, 0, bx * BN, z * 128,
                     x2full + 2048, 4096, Wd_bf, DD,
                     att2_part + (size_t)z * astride, AA,
                     AA, 128, nullptr, nullptr);
    } else {                    // g2h: 64 n-blocks x 4 z, Kc=512, K offset 2048
        int j = idx - 128;
        int bx = j & 63, z = j >> 6;
        gemm_core<0>(As, Wsm, 0, bx * BN, 2048 + z * 512,
                     x2full, 4096, W2cat, 4096,
                     g_part + (size_t)(4 + z) * gstride, 4096,
                     4096, 512, nullptr, nullptr);
    }
}

// ---------------- LSTM pointwise: NZ split-K partials + optional fp32 pre-terms ----------
template<int NZ>
__global__ void lstm_kernel(const float* __restrict__ gpart, size_t pstride,
                            const float* __restrict__ bih, const float* __restrict__ bhh,
                            const float* __restrict__ pre0, const float* __restrict__ pre1,
                            float* __restrict__ c,
                            __hip_bfloat16* __restrict__ hs1, int st1,
                            __hip_bfloat16* __restrict__ hs2, int st2,
                            __hip_bfloat16* __restrict__ hs3,
                            const int* __restrict__ dec_len, int t) {
    int idx = blockIdx.x * 256 + threadIdx.x;   // B*DD threads
    int b = idx >> 10;
    int d = idx & 1023;
    if (t >= dec_len[b]) return;                 // inactive: freeze h,c
    float g[4];
#pragma unroll
    for (int gate = 0; gate < 4; ++gate) {
        size_t o = (size_t)b * 4096 + gate * 1024 + d;
        float s = bih[gate * 1024 + d] + bhh[gate * 1024 + d];
        if (pre0) s += pre0[o];
        if (pre1) s += pre1[o];
#pragma unroll
        for (int z = 0; z < NZ; ++z) s += gpart[z * pstride + o];
        g[gate] = s;
    }
    float si = 1.f / (1.f + expf(-g[0]));
    float sf = 1.f / (1.f + expf(-g[1]));
    float so = 1.f / (1.f + expf(-g[3]));
    float cc = sf * c[idx] + si * tanhf(g[2]);
    float hh = so * tanhf(cc);
    c[idx] = cc;
    __hip_bfloat16 hb = __float2bfloat16(hh);
    hs1[(size_t)b * st1 + d] = hb;
    hs2[(size_t)b * st2 + d] = hb;
    if (hs3) hs3[(size_t)b * 1024 + d] = hb;
}

// ---------------- fused attention: av-reduce + score + softmax + awe (block per b) -------
__global__ __launch_bounds__(1024) void att_fused(
        const float* __restrict__ p, size_t pstride,   // 8 x (B,AA) partials
        const float* __restrict__ bf_,
        const float* __restrict__ bd_,
        float* __restrict__ av_g,                      // (B,AA) scratch
        const __hip_bfloat16* __restrict__ att1,       // (B*NN, AA) bf16
        const float* __restrict__ Wa,                  // (AA)
        const __hip_bfloat16* __restrict__ feats,      // (B, NN, FF) sorted bf16
        __hip_bfloat16* __restrict__ x2full) {         // awe slot, row stride 4096
    int b = blockIdx.x;
    int tid = threadIdx.x;
    __shared__ float esh[NN];
    __shared__ float alpha[NN];

    // phase 1: av = bf + bd + sum_z partials (1 elem/thread, coalesced)
    {
        size_t o = (size_t)b * AA + tid;
        float s = bf_[tid] + bd_[tid];
#pragma unroll
        for (int z = 0; z < 8; ++z) s += p[z * pstride + o];
        av_g[o] = s;
    }
    __syncthreads();

    // phase 2: scores, wave per n (16 waves)
    int wv = tid >> 6, lane = tid & 63;
    const float* avp = av_g + (size_t)b * AA + lane * 16;
    const float* wap = Wa + lane * 16;
    for (int n = wv; n < NN; n += 16) {
        const __hip_bfloat16* a1 = att1 + ((size_t)b * NN + n) * AA + lane * 16;
        float pacc = 0.f;
#pragma unroll
        for (int h = 0; h < 2; ++h) {
            short8 a8 = *(const short8*)(a1 + h * 8);
            floatx4 v0 = *(const floatx4*)(avp + h * 8);
            floatx4 v1 = *(const floatx4*)(avp + h * 8 + 4);
            floatx4 w0 = *(const floatx4*)(wap + h * 8);
            floatx4 w1 = *(const floatx4*)(wap + h * 8 + 4);
            float af[8];
#pragma unroll
            for (int q = 0; q < 8; ++q) {
                union { short s; __hip_bfloat16 b; } u; u.s = a8[q];
                af[q] = __bfloat162float(u.b);
            }
#pragma unroll
            for (int q = 0; q < 4; ++q) {
                pacc += fmaxf(af[q] + v0[q], 0.f) * w0[q];
                pacc += fmaxf(af[4 + q] + v1[q], 0.f) * w1[q];
            }
        }
        for (int off = 32; off; off >>= 1) pacc += __shfl_down(pacc, off);
        if (lane == 0) esh[n] = pacc;
    }
    __syncthreads();

    // phase 3: softmax over NN=36 on wave 0
    if (tid < 64) {
        float ev = (tid < NN) ? esh[tid] : -INFINITY;
        float m = ev;
        for (int off = 32; off; off >>= 1) m = fmaxf(m, __shfl_down(m, off));
        m = __shfl(m, 0);
        float ex = (tid < NN) ? expf(ev - m) : 0.f;
        float s = ex;
        for (int off = 32; off; off >>= 1) s += __shfl_down(s, off);
        s = __shfl(s, 0);
        if (tid < NN) alpha[tid] = ex / s;
    }
    __syncthreads();

    // phase 4: awe — 2 cols/thread (1024*2 = 2048), coalesced 4B/lane
    int f0 = tid * 2;
    const __hip_bfloat16* src = feats + (size_t)b * (NN * FF) + f0;
    float s0 = 0.f, s1 = 0.f;
#pragma unroll
    for (int n = 0; n < NN; ++n) {
        __hip_bfloat162 v = *(const __hip_bfloat162*)(src + n * FF);
        float al = alpha[n];
        s0 += al * __bfloat162float(v.x);
        s1 += al * __bfloat162float(v.y);
    }
    __hip_bfloat162 o;
    o.x = __float2bfloat16(s0);
    o.y = __float2bfloat16(s1);
    *(__hip_bfloat162*)(x2full + (size_t)b * 4096 + f0) = o;
}

// ---------------- host launcher ----------------
extern "C" void kernel_launch(void* const* d_in, const int* in_sizes, int n_in,
                              void* d_out, int out_size, void* d_ws, size_t ws_size,
                              hipStream_t stream) {
    const float* img     = (const float*)d_in[0];
    const int*   caps    = (const int*)d_in[1];
    const int*   cap_len = (const int*)d_in[2];
    const float* emb     = (const float*)d_in[3];
    const float* W1_ih   = (const float*)d_in[4];
    const float* W1_hh   = (const float*)d_in[5];
    const float* b1_ih   = (const float*)d_in[6];
    const float* b1_hh   = (const float*)d_in[7];
    const float* W2_ih   = (const float*)d_in[8];
    const float* W2_hh   = (const float*)d_in[9];
    const float* b2_ih   = (const float*)d_in[10];
    const float* b2_hh   = (const float*)d_in[11];
    const float* Wf      = (const float*)d_in[12];
    const float* bf      = (const float*)d_in[13];
    const float* Wd      = (const float*)d_in[14];
    const float* bd      = (const float*)d_in[15];
    const float* Wa      = (const float*)d_in[16];
    // d_in[17] = ba: softmax shift-invariant, unused
    const float* Wfc     = (const float*)d_in[18];
    const float* bfc     = (const float*)d_in[19];
    float* out = (float*)d_out;
    (void)in_sizes; (void)n_in; (void)out_size; (void)ws_size;

    char* ws = (char*)d_ws;
    size_t off = 0;
    auto alloc = [&](size_t bytes) -> void* {
        void* p = ws + off;
        off += (bytes + 255) & ~(size_t)255;
        return p;
    };
    int* sort_ind = (int*)alloc(B * sizeof(int));
    int* dec_len  = (int*)alloc(B * sizeof(int));
    __hip_bfloat16* W1dyn    = (__hip_bfloat16*)alloc((size_t)4096 * 2048 * 2);
    __hip_bfloat16* W1fm     = (__hip_bfloat16*)alloc((size_t)4096 * 2048 * 2);
    __hip_bfloat16* W1emb    = (__hip_bfloat16*)alloc((size_t)4096 * 1024 * 2);
    __hip_bfloat16* W2cat    = (__hip_bfloat16*)alloc((size_t)4096 * 4096 * 2);
    __hip_bfloat16* Wd_bf    = (__hip_bfloat16*)alloc((size_t)AA * DD * 2);
    __hip_bfloat16* Wfc_bf   = (__hip_bfloat16*)alloc((size_t)VV * DD * 2);
    __hip_bfloat16* Wf_bf    = (__hip_bfloat16*)alloc((size_t)AA * FF * 2);
    __hip_bfloat16* feats_bf = (__hip_bfloat16*)alloc((size_t)B * NN * FF * 2);
    __hip_bfloat16* att1_bf  = (__hip_bfloat16*)alloc((size_t)B * NN * AA * 2);
    __hip_bfloat16* fmbf     = (__hip_bfloat16*)alloc((size_t)B * 2048 * 2);
    __hip_bfloat16* embcat   = (__hip_bfloat16*)alloc((size_t)TT * B * EE * 2);
    float* gpre_fm   = (float*)alloc((size_t)B * 4096 * 4);
    float* gpre_emb  = (float*)alloc((size_t)TT * B * 4096 * 4);
    float* g_part    = (float*)alloc((size_t)8 * B * 4096 * 4);
    float* att2_part = (float*)alloc((size_t)8 * B * AA * 4);
    float* av        = (float*)alloc((size_t)B * AA * 4);
    // --- zero-init region: contiguous so one memset covers all (sizes are 256B-multiples) ---
    char* zbase = (char*)alloc(0);
    __hip_bfloat16* h2hist = (__hip_bfloat16*)alloc((size_t)TT * B * DD * 2);
    __hip_bfloat16* x1dyn  = (__hip_bfloat16*)alloc((size_t)B * 2048 * 2); // [h2|h1]
    __hip_bfloat16* x2full = (__hip_bfloat16*)alloc((size_t)B * 4096 * 2); // [awe|h1|h2]
    float* c1 = (float*)alloc((size_t)B * DD * 4);
    float* c2 = (float*)alloc((size_t)B * DD * 4);
    size_t zlen = (char*)alloc(0) - zbase;

    const size_t gstride = (size_t)B * 4096;
    const size_t astride = (size_t)B * AA;

    // ---- setup ----
    sort_kernel<<<1, B, 0, stream>>>(cap_len, sort_ind, dec_len);
    // all packs/converts + feats gather, 8 elems/thread (60,571,648 elems / 8 / 256 = 29576)
    pack_all_kernel<<<29576, 256, 0, stream>>>(
        W1_ih, W1_hh, W2_ih, W2_hh, Wd, Wfc, Wf, img, sort_ind,
        W1dyn, W1fm, W1emb, W2cat, Wd_bf, Wfc_bf, Wf_bf, feats_bf);
    fm_kernel<<<(B * 2048) / 4 / 256, 256, 0, stream>>>(img, sort_ind, fmbf);
    embcat_kernel<<<(TT * B * EE) / 8 / 256, 256, 0, stream>>>(emb, caps, sort_ind, embcat);
    hipMemsetAsync(zbase, 0, zlen, stream);   // h2hist + x1dyn + x2full + c1 + c2

    // att1 + gpre_emb + gpre_fm in one launch (576 + 1216 + 64 = 1856 blocks)
    gemm_setup<<<1856, 256, 0, stream>>>(
        feats_bf, Wf_bf, att1_bf, embcat, W1emb, gpre_emb, fmbf, W1fm, gpre_fm);

    for (int t = 0; t < TT; ++t) {
        // D1: g1dyn = [h2|h1] @ W1dyn^T : K=2048, split-K 4 (Kc=512) -> slices 0..3
        gemm_bf16<0><<<dim3(4096 / BN, 1, 4), 256, 0, stream>>>(
            x1dyn, 2048, W1dyn, 2048, g_part, 4096, gstride, 4096, 512,
            nullptr, nullptr);

        // D2: lstm1 = sum(4 partials) + gpre_fm + gpre_emb[t] + biases -> h1
        lstm_kernel<4><<<(B * DD) / 256, 256, 0, stream>>>(
            g_part, gstride, b1_ih, b1_hh,
            gpre_fm, gpre_emb + (size_t)t * B * 4096, c1,
            x1dyn + 1024, 2048, x2full + 2048, 4096, nullptr, dec_len, t);

        // D3: att2 partials (h1@Wd^T, split8) + g2h ([h1|h2]@W2[:,2048:], split4 -> slices 4..7)
        gemm_d3<<<128 + 256, 256, 0, stream>>>(
            x2full, Wd_bf, W2cat, att2_part, astride, g_part, gstride);

        // D4: fused av-reduce + score + softmax + awe (1024 threads/block)
        att_fused<<<B, 1024, 0, stream>>>(att2_part, astride, bf, bd, av,
                                          att1_bf, Wa, feats_bf, x2full);

        // D5: g2awe = awe @ W2[:,0:2048]^T : split-K 4 (Kc=512) -> slices 0..3
        gemm_bf16<0><<<dim3(4096 / BN, 1, 4), 256, 0, stream>>>(
            x2full, 4096, W2cat, 4096, g_part, 4096, gstride, 4096, 512,
            nullptr, nullptr);

        // D6: lstm2 = sum(8 partials: awe 0..3 + h 4..7) + biases -> h2 (+h2hist[t])
        lstm_kernel<8><<<(B * DD) / 256, 256, 0, stream>>>(
            g_part, gstride, b2_ih, b2_hh, nullptr, nullptr, c2,
            x1dyn + 0, 2048, x2full + 3072, 4096,
            h2hist + (size_t)t * B * DD, dec_len, t);
    }

    // batched preds: h2hist (2432 x 1024) @ Wfc^T, masked + bias.
    // grid.x padded 157 -> 160 (multiple of 8 XCDs) for L2-stable Wfc panels.
    gemm_bf16<3><<<dim3(160, TT, 1), 256, 0, stream>>>(
        h2hist, DD, Wfc_bf, DD, out, TT * VV, 0, VV, DD, bfc, dec_len);
}

// Round 10
// 1479.078 us; speedup vs baseline: 5.4705x; 1.0163x over previous
//
#include <hip/hip_runtime.h>
#include <hip/hip_bf16.h>
#include <math.h>

#define B   128
#define NN  36
#define FF  2048
#define AA  1024
#define EE  1024
#define DD  1024
#define VV  10000
#define LL  20
#define TT  19

typedef __attribute__((ext_vector_type(8))) short short8;
typedef __attribute__((ext_vector_type(4))) float floatx4;

__device__ __forceinline__ short f2bs(float x) {
    union { __hip_bfloat16 b; short s; } u; u.b = __float2bfloat16(x); return u.s;
}
// convert 8 contiguous fp32 -> 8 bf16 (32B load, 16B store)
__device__ __forceinline__ void cvt8(const float* __restrict__ s, __hip_bfloat16* __restrict__ d) {
    floatx4 a = *(const floatx4*)s;
    floatx4 b = *(const floatx4*)(s + 4);
    short8 o;
    o[0] = f2bs(a[0]); o[1] = f2bs(a[1]); o[2] = f2bs(a[2]); o[3] = f2bs(a[3]);
    o[4] = f2bs(b[0]); o[5] = f2bs(b[1]); o[6] = f2bs(b[2]); o[7] = f2bs(b[3]);
    *(short8*)d = o;
}

// ---------------- sort (stable descending by length) ----------------
__global__ __launch_bounds__(B) void sort_kernel(const int* __restrict__ cap_len,
                                                 int* __restrict__ sort_ind,
                                                 int* __restrict__ dec_len) {
    __shared__ int lsh[B];
    int i = threadIdx.x;
    lsh[i] = cap_len[i];
    __syncthreads();
    int li = lsh[i];
    int rank = 0;
    for (int j = 0; j < B; ++j) {
        int lj = lsh[j];
        rank += (lj > li) || (lj == li && j < i);   // stable descending
    }
    sort_ind[rank] = i;
    dec_len[rank]  = li - 1;
}

// ---------------- one launch for all weight packs/converts + feats gather (8 elems/thread) ----
// Segment element offsets (all multiples of 8; row-splits at 1024/3072 also multiples of 8):
//   [0,        8388608)  W1dyn = [W1_ih[:,0:1024] | W1_hh]      (4096 x 2048)
//   [8388608, 16777216)  W1fm  = W1_ih[:,1024:3072]             (4096 x 2048)
//   [16777216,20971520)  W1emb = W1_ih[:,3072:4096]             (4096 x 1024)
//   [20971520,37748736)  W2cat = [W2_ih | W2_hh]                (4096 x 4096)
//   [37748736,38797312)  Wd_bf                                  (1024 x 1024)
//   [38797312,49037312)  Wfc_bf                                 (10000 x 1024)
//   [49037312,51134464)  Wf_bf                                  (1024 x 2048)
//   [51134464,60571648)  feats_bf (sorted gather)               (128 x 36 x 2048)
__global__ void pack_all_kernel(const float* __restrict__ W1_ih, const float* __restrict__ W1_hh,
                                const float* __restrict__ W2_ih, const float* __restrict__ W2_hh,
                                const float* __restrict__ Wd,    const float* __restrict__ Wfc,
                                const float* __restrict__ Wf,    const float* __restrict__ img,
                                const int* __restrict__ sort_ind,
                                __hip_bfloat16* __restrict__ W1dyn, __hip_bfloat16* __restrict__ W1fm,
                                __hip_bfloat16* __restrict__ W1emb, __hip_bfloat16* __restrict__ W2cat,
                                __hip_bfloat16* __restrict__ Wd_bf, __hip_bfloat16* __restrict__ Wfc_bf,
                                __hip_bfloat16* __restrict__ Wf_bf, __hip_bfloat16* __restrict__ feats_bf) {
    size_t idx = ((size_t)blockIdx.x * 256 + threadIdx.x) * 8;
    const float* src;
    __hip_bfloat16* dst;
    if (idx < 8388608UL) {
        size_t i = idx; int n = (int)(i >> 11), k = (int)(i & 2047);
        src = (k < 1024) ? (W1_ih + (size_t)n * 4096 + k) : (W1_hh + (size_t)n * 1024 + (k - 1024));
        dst = W1dyn + i;
    } else if (idx < 16777216UL) {
        size_t i = idx - 8388608UL; int n = (int)(i >> 11), k = (int)(i & 2047);
        src = W1_ih + (size_t)n * 4096 + 1024 + k;
        dst = W1fm + i;
    } else if (idx < 20971520UL) {
        size_t i = idx - 16777216UL; int n = (int)(i >> 10), k = (int)(i & 1023);
        src = W1_ih + (size_t)n * 4096 + 3072 + k;
        dst = W1emb + i;
    } else if (idx < 37748736UL) {
        size_t i = idx - 20971520UL; int n = (int)(i >> 12), k = (int)(i & 4095);
        src = (k < 3072) ? (W2_ih + (size_t)n * 3072 + k) : (W2_hh + (size_t)n * 1024 + (k - 3072));
        dst = W2cat + i;
    } else if (idx < 38797312UL) {
        size_t i = idx - 37748736UL;
        src = Wd + i;  dst = Wd_bf + i;
    } else if (idx < 49037312UL) {
        size_t i = idx - 38797312UL;
        src = Wfc + i; dst = Wfc_bf + i;
    } else if (idx < 51134464UL) {
        size_t i = idx - 49037312UL;
        src = Wf + i;  dst = Wf_bf + i;
    } else {
        size_t i = idx - 51134464UL;
        int b = (int)(i / (NN * FF));
        int r = (int)(i % (NN * FF));
        src = img + (size_t)sort_ind[b] * (NN * FF) + r;
        dst = feats_bf + i;
    }
    cvt8(src, dst);
}

// ---------------- feats_mean -> fmbf (128 x 2048 bf16), 4 cols/thread ----------------
__global__ void fm_kernel(const float* __restrict__ img,
                          const int* __restrict__ sort_ind,
                          __hip_bfloat16* __restrict__ fmbf) {
    int i = (blockIdx.x * 256 + threadIdx.x) * 4;   // B*2048/4 threads
    int b = i >> 11;
    int f = i & 2047;
    const float* src = img + (size_t)sort_ind[b] * (NN * FF) + f;
    floatx4 s = (floatx4){0.f, 0.f, 0.f, 0.f};
#pragma unroll
    for (int n = 0; n < NN; ++n) {
        floatx4 v = *(const floatx4*)(src + (size_t)n * FF);
        s[0] += v[0]; s[1] += v[1]; s[2] += v[2]; s[3] += v[3];
    }
    short o4[4];
#pragma unroll
    for (int q = 0; q < 4; ++q) o4[q] = f2bs(s[q] * (1.0f / NN));
    *(uint2*)(fmbf + i) = *(uint2*)o4;
}

// ---------------- embcat gather (8 elems/thread): row t*128+b = emb[caps[sorted_b][t]] ----
__global__ void embcat_kernel(const float* __restrict__ emb,
                              const int* __restrict__ caps,
                              const int* __restrict__ sort_ind,
                              __hip_bfloat16* __restrict__ embcat) {
    size_t i = ((size_t)blockIdx.x * 256 + threadIdx.x) * 8;   // TT*B*EE elems
    int row = (int)(i >> 10);
    int e = (int)(i & 1023);
    int t = row >> 7;       // row = t*128 + b
    int b = row & 127;
    int cap = caps[sort_ind[b] * LL + t];
    cvt8(emb + (size_t)cap * EE + e, embcat + i);
}

// ---------------- bf16 MFMA GEMM core ----------------
// EPI=0: fp32 partial at C. EPI=2: bf16 output (att1).
// EPI=3: batched preds epilogue: row = t*128+b; mask by (t < dec_len[b]); +bias; N guard.
#define BM 128
#define BN 64
#define BK 64
#define LDS_K 72

template<int EPI>
__device__ __forceinline__ void gemm_core(
        short (*As)[LDS_K], short (*Wsm)[LDS_K],
        int bm, int bn, int k0,
        const __hip_bfloat16* __restrict__ A, int lda,
        const __hip_bfloat16* __restrict__ W, int ldw,
        float* __restrict__ C, int ldc,
        int N, int Kc,
        const float* __restrict__ bias,
        const int* __restrict__ dec_len) {
    const int tid  = threadIdx.x;
    const int lane = tid & 63;
    const int wv   = tid >> 6;
    const int quad = lane >> 4;
    const int l15  = lane & 15;
    const int wm   = (wv >> 1) * 64;
    const int wn   = (wv & 1) * 32;
    const int srow = tid >> 3;
    const int scol = (tid & 7) * 8;

    floatx4 acc[4][2];
#pragma unroll
    for (int i = 0; i < 4; ++i)
#pragma unroll
        for (int j = 0; j < 2; ++j)
            acc[i][j] = (floatx4){0.f, 0.f, 0.f, 0.f};

    const __hip_bfloat16* Aptr = A + (size_t)(bm + srow) * lda + k0 + scol;
    const __hip_bfloat16* Wptr = W + k0 + scol;

    for (int kt = 0; kt < Kc; kt += BK) {
#pragma unroll
        for (int p = 0; p < 4; ++p) {
            floatx4 v = *(const floatx4*)(Aptr + (size_t)(p * 32) * lda + kt);
            *(floatx4*)(&As[p * 32 + srow][scol]) = v;
        }
#pragma unroll
        for (int p = 0; p < 2; ++p) {
            int gw = bn + p * 32 + srow;
            floatx4 v;
            if (EPI != 3 || gw < N)
                v = *(const floatx4*)(Wptr + (size_t)gw * ldw + kt);
            else
                v = (floatx4){0.f, 0.f, 0.f, 0.f};
            *(floatx4*)(&Wsm[p * 32 + srow][scol]) = v;
        }
        __syncthreads();
#pragma unroll
        for (int ks = 0; ks < 2; ++ks) {
            short8 af[4], bw[2];
#pragma unroll
            for (int i = 0; i < 4; ++i)
                af[i] = *(const short8*)(&As[wm + i * 16 + l15][ks * 32 + quad * 8]);
#pragma unroll
            for (int j = 0; j < 2; ++j)
                bw[j] = *(const short8*)(&Wsm[wn + j * 16 + l15][ks * 32 + quad * 8]);
#pragma unroll
            for (int i = 0; i < 4; ++i)
#pragma unroll
                for (int j = 0; j < 2; ++j)
                    acc[i][j] = __builtin_amdgcn_mfma_f32_16x16x32_bf16(
                        af[i], bw[j], acc[i][j], 0, 0, 0);
        }
        __syncthreads();
    }

    // D layout: row = quad*4+reg, col = lane&15 (m89-verified)
#pragma unroll
    for (int i = 0; i < 4; ++i) {
        int m = bm + wm + i * 16 + quad * 4;
#pragma unroll
        for (int j = 0; j < 2; ++j) {
            int n = bn + wn + j * 16 + l15;
            if (EPI == 3 && n >= N) continue;
#pragma unroll
            for (int r = 0; r < 4; ++r) {
                float v = acc[i][j][r];
                if (EPI == 3) {
                    int row = m + r;
                    int tt = row >> 7;          // row = t*128 + b
                    int bb = row & 127;
                    bool act = tt < dec_len[bb];
                    C[(size_t)bb * (TT * VV) + (size_t)tt * VV + n] =
                        act ? (v + bias[n]) : 0.f;
                } else if (EPI == 2) {
                    ((__hip_bfloat16*)C)[(size_t)(m + r) * ldc + n] = __float2bfloat16(v);
                } else {
                    C[(size_t)(m + r) * ldc + n] = v;
                }
            }
        }
    }
}

// ---------------- standalone GEMM wrapper (grid.x may be XCD-padded) ----------------
template<int EPI>
__global__ __launch_bounds__(256) void gemm_bf16(
        const __hip_bfloat16* __restrict__ A, int lda,
        const __hip_bfloat16* __restrict__ W, int ldw,
        float* __restrict__ C, int ldc, size_t pstride,
        int N, int Kc,
        const float* __restrict__ bias,
        const int* __restrict__ dec_len) {
    if (blockIdx.x * BN >= N) return;           // grid padding guard
    __shared__ __align__(16) short As[BM][LDS_K];
    __shared__ __align__(16) short Wsm[BN][LDS_K];
    gemm_core<EPI>(As, Wsm, blockIdx.y * BM, blockIdx.x * BN, blockIdx.z * Kc,
                   A, lda, W, ldw, C + (size_t)blockIdx.z * pstride, ldc,
                   N, Kc, bias, dec_len);
}

// ---------------- setup GEMMs in one launch: att1 (576) + gpre_emb (1216) + gpre_fm (64) ----
__global__ __launch_bounds__(256) void gemm_setup(
        const __hip_bfloat16* __restrict__ feats_bf, const __hip_bfloat16* __restrict__ Wf_bf,
        __hip_bfloat16* __restrict__ att1_bf,
        const __hip_bfloat16* __restrict__ embcat,   const __hip_bfloat16* __restrict__ W1emb,
        float* __restrict__ gpre_emb,
        const __hip_bfloat16* __restrict__ fmbf,     const __hip_bfloat16* __restrict__ W1fm,
        float* __restrict__ gpre_fm) {
    __shared__ __align__(16) short As[BM][LDS_K];
    __shared__ __align__(16) short Wsm[BN][LDS_K];
    int idx = blockIdx.x;
    if (idx < 576) {            // att1: (36 x 16) tiles, M=4608, N=1024, K=2048
        gemm_core<2>(As, Wsm, (idx >> 4) * BM, (idx & 15) * BN, 0,
                     feats_bf, FF, Wf_bf, FF, (float*)att1_bf, AA,
                     AA, FF, nullptr, nullptr);
    } else if (idx < 1792) {    // gpre_emb: (19 x 64) tiles, M=2432, N=4096, K=1024
        int j = idx - 576;
        gemm_core<0>(As, Wsm, (j >> 6) * BM, (j & 63) * BN, 0,
                     embcat, EE, W1emb, EE, gpre_emb, 4096,
                     4096, EE, nullptr, nullptr);
    } else {                    // gpre_fm: 64 tiles, M=128, N=4096, K=2048
        int j = idx - 1792;
        gemm_core<0>(As, Wsm, 0, j * BN, 0,
                     fmbf, 2048, W1fm, 2048, gpre_fm, 4096,
                     4096, 2048, nullptr, nullptr);
    }
}

// ---------------- D3: att2 (h1@Wd^T, split8) + g2h ([h1|h2]@W2[:,2048:]^T, split8) ----------
// g2h writes slices 8..15 (Kc=256); att2 writes its own 8 partials.
__global__ __launch_bounds__(256) void gemm_d3(
        const __hip_bfloat16* __restrict__ x2full,
        const __hip_bfloat16* __restrict__ Wd_bf,
        const __hip_bfloat16* __restrict__ W2cat,
        float* __restrict__ att2_part, size_t astride,
        float* __restrict__ g_part, size_t gstride) {
    __shared__ __align__(16) short As[BM][LDS_K];
    __shared__ __align__(16) short Wsm[BN][LDS_K];
    int idx = blockIdx.x;
    if (idx < 128) {            // att2: 16 n-blocks x 8 z, Kc=128
        int bx = idx & 15, z = idx >> 4;
        gemm_core<0>(As, Wsm, 0, bx * BN, z * 128,
                     x2full + 2048, 4096, Wd_bf, DD,
                     att2_part + (size_t)z * astride, AA,
                     AA, 128, nullptr, nullptr);
    } else {                    // g2h: 64 n-blocks x 8 z, Kc=256, K offset 2048
        int j = idx - 128;
        int bx = j & 63, z = j >> 6;
        gemm_core<0>(As, Wsm, 0, bx * BN, 2048 + z * 256,
                     x2full, 4096, W2cat, 4096,
                     g_part + (size_t)(8 + z) * gstride, 4096,
                     4096, 256, nullptr, nullptr);
    }
}

// ---------------- LSTM pointwise: NZ split-K partials + optional fp32 pre-terms ----------
template<int NZ>
__global__ void lstm_kernel(const float* __restrict__ gpart, size_t pstride,
                            const float* __restrict__ bih, const float* __restrict__ bhh,
                            const float* __restrict__ pre0, const float* __restrict__ pre1,
                            float* __restrict__ c,
                            __hip_bfloat16* __restrict__ hs1, int st1,
                            __hip_bfloat16* __restrict__ hs2, int st2,
                            __hip_bfloat16* __restrict__ hs3,
                            const int* __restrict__ dec_len, int t) {
    int idx = blockIdx.x * 256 + threadIdx.x;   // B*DD threads
    int b = idx >> 10;
    int d = idx & 1023;
    if (t >= dec_len[b]) return;                 // inactive: freeze h,c
    float g[4];
#pragma unroll
    for (int gate = 0; gate < 4; ++gate) {
        size_t o = (size_t)b * 4096 + gate * 1024 + d;
        float s = bih[gate * 1024 + d] + bhh[gate * 1024 + d];
        if (pre0) s += pre0[o];
        if (pre1) s += pre1[o];
#pragma unroll
        for (int z = 0; z < NZ; ++z) s += gpart[z * pstride + o];
        g[gate] = s;
    }
    float si = 1.f / (1.f + expf(-g[0]));
    float sf = 1.f / (1.f + expf(-g[1]));
    float so = 1.f / (1.f + expf(-g[3]));
    float cc = sf * c[idx] + si * tanhf(g[2]);
    float hh = so * tanhf(cc);
    c[idx] = cc;
    __hip_bfloat16 hb = __float2bfloat16(hh);
    hs1[(size_t)b * st1 + d] = hb;
    hs2[(size_t)b * st2 + d] = hb;
    if (hs3) hs3[(size_t)b * 1024 + d] = hb;
}

// ---------------- fused attention: av-reduce + score + softmax + awe (block per b) -------
__global__ __launch_bounds__(1024) void att_fused(
        const float* __restrict__ p, size_t pstride,   // 8 x (B,AA) partials
        const float* __restrict__ bf_,
        const float* __restrict__ bd_,
        float* __restrict__ av_g,                      // (B,AA) scratch
        const __hip_bfloat16* __restrict__ att1,       // (B*NN, AA) bf16
        const float* __restrict__ Wa,                  // (AA)
        const __hip_bfloat16* __restrict__ feats,      // (B, NN, FF) sorted bf16
        __hip_bfloat16* __restrict__ x2full) {         // awe slot, row stride 4096
    int b = blockIdx.x;
    int tid = threadIdx.x;
    __shared__ float esh[NN];
    __shared__ float alpha[NN];

    // phase 1: av = bf + bd + sum_z partials (1 elem/thread, coalesced)
    {
        size_t o = (size_t)b * AA + tid;
        float s = bf_[tid] + bd_[tid];
#pragma unroll
        for (int z = 0; z < 8; ++z) s += p[z * pstride + o];
        av_g[o] = s;
    }
    __syncthreads();

    // phase 2: scores, wave per n (16 waves)
    int wv = tid >> 6, lane = tid & 63;
    const float* avp = av_g + (size_t)b * AA + lane * 16;
    const float* wap = Wa + lane * 16;
    for (int n = wv; n < NN; n += 16) {
        const __hip_bfloat16* a1 = att1 + ((size_t)b * NN + n) * AA + lane * 16;
        float pacc = 0.f;
#pragma unroll
        for (int h = 0; h < 2; ++h) {
            short8 a8 = *(const short8*)(a1 + h * 8);
            floatx4 v0 = *(const floatx4*)(avp + h * 8);
            floatx4 v1 = *(const floatx4*)(avp + h * 8 + 4);
            floatx4 w0 = *(const floatx4*)(wap + h * 8);
            floatx4 w1 = *(const floatx4*)(wap + h * 8 + 4);
            float af[8];
#pragma unroll
            for (int q = 0; q < 8; ++q) {
                union { short s; __hip_bfloat16 b; } u; u.s = a8[q];
                af[q] = __bfloat162float(u.b);
            }
#pragma unroll
            for (int q = 0; q < 4; ++q) {
                pacc += fmaxf(af[q] + v0[q], 0.f) * w0[q];
                pacc += fmaxf(af[4 + q] + v1[q], 0.f) * w1[q];
            }
        }
        for (int off = 32; off; off >>= 1) pacc += __shfl_down(pacc, off);
        if (lane == 0) esh[n] = pacc;
    }
    __syncthreads();

    // phase 3: softmax over NN=36 on wave 0
    if (tid < 64) {
        float ev = (tid < NN) ? esh[tid] : -INFINITY;
        float m = ev;
        for (int off = 32; off; off >>= 1) m = fmaxf(m, __shfl_down(m, off));
        m = __shfl(m, 0);
        float ex = (tid < NN) ? expf(ev - m) : 0.f;
        float s = ex;
        for (int off = 32; off; off >>= 1) s += __shfl_down(s, off);
        s = __shfl(s, 0);
        if (tid < NN) alpha[tid] = ex / s;
    }
    __syncthreads();

    // phase 4: awe — 2 cols/thread (1024*2 = 2048), coalesced 4B/lane
    int f0 = tid * 2;
    const __hip_bfloat16* src = feats + (size_t)b * (NN * FF) + f0;
    float s0 = 0.f, s1 = 0.f;
#pragma unroll
    for (int n = 0; n < NN; ++n) {
        __hip_bfloat162 v = *(const __hip_bfloat162*)(src + n * FF);
        float al = alpha[n];
        s0 += al * __bfloat162float(v.x);
        s1 += al * __bfloat162float(v.y);
    }
    __hip_bfloat162 o;
    o.x = __float2bfloat16(s0);
    o.y = __float2bfloat16(s1);
    *(__hip_bfloat162*)(x2full + (size_t)b * 4096 + f0) = o;
}

// ---------------- host launcher ----------------
extern "C" void kernel_launch(void* const* d_in, const int* in_sizes, int n_in,
                              void* d_out, int out_size, void* d_ws, size_t ws_size,
                              hipStream_t stream) {
    const float* img     = (const float*)d_in[0];
    const int*   caps    = (const int*)d_in[1];
    const int*   cap_len = (const int*)d_in[2];
    const float* emb     = (const float*)d_in[3];
    const float* W1_ih   = (const float*)d_in[4];
    const float* W1_hh   = (const float*)d_in[5];
    const float* b1_ih   = (const float*)d_in[6];
    const float* b1_hh   = (const float*)d_in[7];
    const float* W2_ih   = (const float*)d_in[8];
    const float* W2_hh   = (const float*)d_in[9];
    const float* b2_ih   = (const float*)d_in[10];
    const float* b2_hh   = (const float*)d_in[11];
    const float* Wf      = (const float*)d_in[12];
    const float* bf      = (const float*)d_in[13];
    const float* Wd      = (const float*)d_in[14];
    const float* bd      = (const float*)d_in[15];
    const float* Wa      = (const float*)d_in[16];
    // d_in[17] = ba: softmax shift-invariant, unused
    const float* Wfc     = (const float*)d_in[18];
    const float* bfc     = (const float*)d_in[19];
    float* out = (float*)d_out;
    (void)in_sizes; (void)n_in; (void)out_size; (void)ws_size;

    char* ws = (char*)d_ws;
    size_t off = 0;
    auto alloc = [&](size_t bytes) -> void* {
        void* p = ws + off;
        off += (bytes + 255) & ~(size_t)255;
        return p;
    };
    int* sort_ind = (int*)alloc(B * sizeof(int));
    int* dec_len  = (int*)alloc(B * sizeof(int));
    __hip_bfloat16* W1dyn    = (__hip_bfloat16*)alloc((size_t)4096 * 2048 * 2);
    __hip_bfloat16* W1fm     = (__hip_bfloat16*)alloc((size_t)4096 * 2048 * 2);
    __hip_bfloat16* W1emb    = (__hip_bfloat16*)alloc((size_t)4096 * 1024 * 2);
    __hip_bfloat16* W2cat    = (__hip_bfloat16*)alloc((size_t)4096 * 4096 * 2);
    __hip_bfloat16* Wd_bf    = (__hip_bfloat16*)alloc((size_t)AA * DD * 2);
    __hip_bfloat16* Wfc_bf   = (__hip_bfloat16*)alloc((size_t)VV * DD * 2);
    __hip_bfloat16* Wf_bf    = (__hip_bfloat16*)alloc((size_t)AA * FF * 2);
    __hip_bfloat16* feats_bf = (__hip_bfloat16*)alloc((size_t)B * NN * FF * 2);
    __hip_bfloat16* att1_bf  = (__hip_bfloat16*)alloc((size_t)B * NN * AA * 2);
    __hip_bfloat16* fmbf     = (__hip_bfloat16*)alloc((size_t)B * 2048 * 2);
    __hip_bfloat16* embcat   = (__hip_bfloat16*)alloc((size_t)TT * B * EE * 2);
    float* gpre_fm   = (float*)alloc((size_t)B * 4096 * 4);
    float* gpre_emb  = (float*)alloc((size_t)TT * B * 4096 * 4);
    float* g_part    = (float*)alloc((size_t)16 * B * 4096 * 4);   // 16 slices (split-K 8 x2)
    float* att2_part = (float*)alloc((size_t)8 * B * AA * 4);
    float* av        = (float*)alloc((size_t)B * AA * 4);
    // --- zero-init region: contiguous so one memset covers all (sizes are 256B-multiples) ---
    char* zbase = (char*)alloc(0);
    __hip_bfloat16* h2hist = (__hip_bfloat16*)alloc((size_t)TT * B * DD * 2);
    __hip_bfloat16* x1dyn  = (__hip_bfloat16*)alloc((size_t)B * 2048 * 2); // [h2|h1]
    __hip_bfloat16* x2full = (__hip_bfloat16*)alloc((size_t)B * 4096 * 2); // [awe|h1|h2]
    float* c1 = (float*)alloc((size_t)B * DD * 4);
    float* c2 = (float*)alloc((size_t)B * DD * 4);
    size_t zlen = (char*)alloc(0) - zbase;

    const size_t gstride = (size_t)B * 4096;
    const size_t astride = (size_t)B * AA;

    // ---- setup ----
    sort_kernel<<<1, B, 0, stream>>>(cap_len, sort_ind, dec_len);
    // all packs/converts + feats gather, 8 elems/thread (60,571,648 elems / 8 / 256 = 29576)
    pack_all_kernel<<<29576, 256, 0, stream>>>(
        W1_ih, W1_hh, W2_ih, W2_hh, Wd, Wfc, Wf, img, sort_ind,
        W1dyn, W1fm, W1emb, W2cat, Wd_bf, Wfc_bf, Wf_bf, feats_bf);
    fm_kernel<<<(B * 2048) / 4 / 256, 256, 0, stream>>>(img, sort_ind, fmbf);
    embcat_kernel<<<(TT * B * EE) / 8 / 256, 256, 0, stream>>>(emb, caps, sort_ind, embcat);
    hipMemsetAsync(zbase, 0, zlen, stream);   // h2hist + x1dyn + x2full + c1 + c2

    // att1 + gpre_emb + gpre_fm in one launch (576 + 1216 + 64 = 1856 blocks)
    gemm_setup<<<1856, 256, 0, stream>>>(
        feats_bf, Wf_bf, att1_bf, embcat, W1emb, gpre_emb, fmbf, W1fm, gpre_fm);

    for (int t = 0; t < TT; ++t) {
        // D1: g1dyn = [h2|h1] @ W1dyn^T : K=2048, split-K 8 (Kc=256) -> slices 0..7
        gemm_bf16<0><<<dim3(4096 / BN, 1, 8), 256, 0, stream>>>(
            x1dyn, 2048, W1dyn, 2048, g_part, 4096, gstride, 4096, 256,
            nullptr, nullptr);

        // D2: lstm1 = sum(8 partials) + gpre_fm + gpre_emb[t] + biases -> h1
        lstm_kernel<8><<<(B * DD) / 256, 256, 0, stream>>>(
            g_part, gstride, b1_ih, b1_hh,
            gpre_fm, gpre_emb + (size_t)t * B * 4096, c1,
            x1dyn + 1024, 2048, x2full + 2048, 4096, nullptr, dec_len, t);

        // D3: att2 partials (h1@Wd^T, split8) + g2h ([h1|h2]@W2[:,2048:], split8 -> slices 8..15)
        gemm_d3<<<128 + 512, 256, 0, stream>>>(
            x2full, Wd_bf, W2cat, att2_part, astride, g_part, gstride);

        // D4: fused av-reduce + score + softmax + awe (1024 threads/block)
        att_fused<<<B, 1024, 0, stream>>>(att2_part, astride, bf, bd, av,
                                          att1_bf, Wa, feats_bf, x2full);

        // D5: g2awe = awe @ W2[:,0:2048]^T : split-K 8 (Kc=256) -> slices 0..7
        gemm_bf16<0><<<dim3(4096 / BN, 1, 8), 256, 0, stream>>>(
            x2full, 4096, W2cat, 4096, g_part, 4096, gstride, 4096, 256,
            nullptr, nullptr);

        // D6: lstm2 = sum(16 partials: awe 0..7 + h 8..15) + biases -> h2 (+h2hist[t])
        lstm_kernel<16><<<(B * DD) / 256, 256, 0, stream>>>(
            g_part, gstride, b2_ih, b2_hh, nullptr, nullptr, c2,
            x1dyn + 0, 2048, x2full + 3072, 4096,
            h2hist + (size_t)t * B * DD, dec_len, t);
    }

    // batched preds: h2hist (2432 x 1024) @ Wfc^T, masked + bias.
    // grid.x padded 157 -> 160 (multiple of 8 XCDs) for L2-stable Wfc panels.
    gemm_bf16<3><<<dim3(160, TT, 1), 256, 0, stream>>>(
        h2hist, DD, Wfc_bf, DD, out, TT * VV, 0, VV, DD, bfc, dec_len);
}